// Round 1
// baseline (2839.539 us; speedup 1.0000x reference)
//
#include <hip/hip_runtime.h>

// ---------------------------------------------------------------------------
// 4-layer transformer decoder, bf16 MFMA implementation.
// L=4, H=16, D=1024, FF=4096, T=S=256, N=16  -> M = T*N = S*N = 4096 rows.
// ---------------------------------------------------------------------------

typedef __attribute__((ext_vector_type(4))) float f32x4;
typedef __attribute__((ext_vector_type(8))) short bf16x8;           // 8 bf16 bit-patterns (4 VGPRs)
typedef __attribute__((ext_vector_type(8))) unsigned short u16x8;
typedef __attribute__((ext_vector_type(4))) unsigned short u16x4;
typedef __attribute__((ext_vector_type(4))) unsigned int   u32x4;

__device__ __forceinline__ unsigned short f2bf(float f) {
    unsigned int u = __builtin_bit_cast(unsigned int, f);
    u += 0x7fffu + ((u >> 16) & 1u);   // RNE
    return (unsigned short)(u >> 16);
}

// ---------------------------------------------------------------------------
// GEMM: out = epilogue( A(bf16)[M][K] @ Bw(f32)[N][K]^T + bias )
// mode 0: out_bf = bf16((acc+bias)*scale)
// mode 1: out_bf = bf16(relu(acc+bias))
// mode 2: out_f  = acc + bias + resid
// Tile 128x128, BK=32, 4 waves (2x2), each wave 64x64 via 4x4 16x16x32 MFMAs.
// LDS layout chunked by k: Xl[chunk=k/8][row][k%8] -> all b128 accesses.
// ---------------------------------------------------------------------------
__global__ __launch_bounds__(256) void gemm_bt(
    const unsigned short* __restrict__ A,
    const float* __restrict__ Bw,
    const float* __restrict__ bias,
    const float* __restrict__ resid,
    unsigned short* __restrict__ outb,
    float* __restrict__ outf,
    int M, int N, int K, float scale, int mode)
{
    __shared__ unsigned short Al[4][128][8];
    __shared__ unsigned short Bl[4][128][8];
    const int tid  = threadIdx.x;
    const int lane = tid & 63;
    const int wid  = tid >> 6;
    const int wr   = (wid >> 1) * 64;
    const int wc   = (wid & 1) * 64;
    const int m0   = blockIdx.y * 128;
    const int n0   = blockIdx.x * 128;
    const int l15  = lane & 15;
    const int l4   = lane >> 4;

    f32x4 acc[4][4];
    #pragma unroll
    for (int mi = 0; mi < 4; ++mi)
        #pragma unroll
        for (int ni = 0; ni < 4; ++ni)
            acc[mi][ni] = (f32x4){0.f, 0.f, 0.f, 0.f};

    for (int k0 = 0; k0 < K; k0 += 32) {
        // stage A (bf16, 128x32): 2 iters x 16B/thread
        // stage B (f32 -> bf16, 128x32): 2 iters x 32B/thread
        #pragma unroll
        for (int i = 0; i < 2; ++i) {
            const int e   = (i * 256 + tid) * 8;
            const int row = e >> 5;
            const int col = e & 31;           // 0,8,16,24
            u32x4 va = *reinterpret_cast<const u32x4*>(&A[(size_t)(m0 + row) * K + (k0 + col)]);
            *reinterpret_cast<u32x4*>(&Al[col >> 3][row][0]) = va;

            const f32x4* bp = reinterpret_cast<const f32x4*>(&Bw[(size_t)(n0 + row) * K + (k0 + col)]);
            f32x4 b0 = bp[0];
            f32x4 b1 = bp[1];
            u16x8 pk;
            pk[0] = f2bf(b0[0]); pk[1] = f2bf(b0[1]); pk[2] = f2bf(b0[2]); pk[3] = f2bf(b0[3]);
            pk[4] = f2bf(b1[0]); pk[5] = f2bf(b1[1]); pk[6] = f2bf(b1[2]); pk[7] = f2bf(b1[3]);
            *reinterpret_cast<u16x8*>(&Bl[col >> 3][row][0]) = pk;
        }
        __syncthreads();

        bf16x8 af[4], bfv[4];
        #pragma unroll
        for (int mi = 0; mi < 4; ++mi)
            af[mi] = *reinterpret_cast<const bf16x8*>(&Al[l4][wr + mi * 16 + l15][0]);
        #pragma unroll
        for (int ni = 0; ni < 4; ++ni)
            bfv[ni] = *reinterpret_cast<const bf16x8*>(&Bl[l4][wc + ni * 16 + l15][0]);
        #pragma unroll
        for (int mi = 0; mi < 4; ++mi)
            #pragma unroll
            for (int ni = 0; ni < 4; ++ni)
                acc[mi][ni] = __builtin_amdgcn_mfma_f32_16x16x32_bf16(af[mi], bfv[ni], acc[mi][ni], 0, 0, 0);
        __syncthreads();
    }

    // epilogue: D layout col = lane&15, row = (lane>>4)*4 + r
    #pragma unroll
    for (int mi = 0; mi < 4; ++mi) {
        #pragma unroll
        for (int ni = 0; ni < 4; ++ni) {
            const int col = n0 + wc + ni * 16 + l15;
            const float bs = bias[col];
            #pragma unroll
            for (int r = 0; r < 4; ++r) {
                const int row = m0 + wr + mi * 16 + l4 * 4 + r;
                const float val = acc[mi][ni][r] + bs;
                if (mode == 0)      outb[(size_t)row * N + col] = f2bf(val * scale);
                else if (mode == 1) outb[(size_t)row * N + col] = f2bf(fmaxf(val, 0.f));
                else                outf[(size_t)row * N + col] = val + resid[(size_t)row * N + col];
            }
        }
    }
}

// ---------------------------------------------------------------------------
// Fused attention: one workgroup per (n,h). T=S=256, hd=64.
// Q is pre-scaled by hd^-0.5 (folded into Q projection epilogue).
// K staged [8 d-chunks][256 s][8]; V staged transposed [32 s-chunks][64 d][8];
// P (per wave) [32 s-chunks][16 t][8]. All MFMA operand reads are b128.
// ---------------------------------------------------------------------------
__global__ __launch_bounds__(256) void attn_fused(
    const unsigned short* __restrict__ Q,
    const unsigned short* __restrict__ Kb,
    const unsigned short* __restrict__ Vb,
    unsigned short* __restrict__ O,
    int causal)
{
    __shared__ unsigned short Kl[8][256][8];        // 32 KB
    __shared__ unsigned short Vt[32][64][8];        // 32 KB
    __shared__ unsigned short Pl[4][32][16][8];     // 32 KB
    const int tid  = threadIdx.x;
    const int lane = tid & 63;
    const int w    = tid >> 6;
    const int n    = blockIdx.x >> 4;
    const int h    = blockIdx.x & 15;
    const int l15  = lane & 15;
    const int l4   = lane >> 4;
    const size_t hoff = (size_t)h * 64;

    #pragma unroll
    for (int i = 0; i < 8; ++i) {
        const int e = i * 256 + tid;
        const int s = e >> 3;
        const int c = e & 7;
        u32x4 kv = *reinterpret_cast<const u32x4*>(&Kb[((size_t)s * 16 + n) * 1024 + hoff + c * 8]);
        *reinterpret_cast<u32x4*>(&Kl[c][s][0]) = kv;
        u32x4 vv = *reinterpret_cast<const u32x4*>(&Vb[((size_t)s * 16 + n) * 1024 + hoff + c * 8]);
        const unsigned short* ve = reinterpret_cast<const unsigned short*>(&vv);
        #pragma unroll
        for (int j = 0; j < 8; ++j)
            Vt[s >> 3][c * 8 + j][s & 7] = ve[j];
    }
    __syncthreads();

    for (int ch = 0; ch < 4; ++ch) {
        const int t0 = w * 64 + ch * 16;
        bf16x8 qa[2];
        #pragma unroll
        for (int ks = 0; ks < 2; ++ks)
            qa[ks] = *reinterpret_cast<const bf16x8*>(
                &Q[((size_t)(t0 + l15) * 16 + n) * 1024 + hoff + ks * 32 + l4 * 8]);

        // scores: 16 s-tiles, K-dim 64 = 2 MFMA each
        f32x4 sc[16];
        #pragma unroll
        for (int st = 0; st < 16; ++st) {
            f32x4 a = (f32x4){0.f, 0.f, 0.f, 0.f};
            #pragma unroll
            for (int ks = 0; ks < 2; ++ks) {
                bf16x8 kf = *reinterpret_cast<const bf16x8*>(&Kl[ks * 4 + l4][st * 16 + l15][0]);
                a = __builtin_amdgcn_mfma_f32_16x16x32_bf16(qa[ks], kf, a, 0, 0, 0);
            }
            sc[st] = a;
        }
        if (causal) {
            #pragma unroll
            for (int st = 0; st < 16; ++st) {
                const int sg = st * 16 + l15;
                #pragma unroll
                for (int r = 0; r < 4; ++r) {
                    const int tg = t0 + l4 * 4 + r;
                    if (sg > tg) sc[st][r] += -1e9f;
                }
            }
        }
        // wave-parallel softmax: row (l4*4+r) spread over the 16 lanes of group l4
        #pragma unroll
        for (int r = 0; r < 4; ++r) {
            float mx = -3.0e38f;
            #pragma unroll
            for (int st = 0; st < 16; ++st) mx = fmaxf(mx, sc[st][r]);
            #pragma unroll
            for (int dd = 1; dd < 16; dd <<= 1) mx = fmaxf(mx, __shfl_xor(mx, dd, 64));
            float sum = 0.f;
            #pragma unroll
            for (int st = 0; st < 16; ++st) {
                const float e = __expf(sc[st][r] - mx);
                sc[st][r] = e;
                sum += e;
            }
            #pragma unroll
            for (int dd = 1; dd < 16; dd <<= 1) sum += __shfl_xor(sum, dd, 64);
            const float inv = 1.f / sum;
            const int rl = l4 * 4 + r;
            #pragma unroll
            for (int st = 0; st < 16; ++st) {
                const int sg = st * 16 + l15;
                Pl[w][sg >> 3][rl][sg & 7] = f2bf(sc[st][r] * inv);
            }
        }
        // O = P @ V : K-dim s=256 in 8 steps of 32, 4 d-tiles
        f32x4 oacc[4];
        #pragma unroll
        for (int dt = 0; dt < 4; ++dt) oacc[dt] = (f32x4){0.f, 0.f, 0.f, 0.f};
        #pragma unroll
        for (int kt = 0; kt < 8; ++kt) {
            bf16x8 pa = *reinterpret_cast<const bf16x8*>(&Pl[w][kt * 4 + l4][l15][0]);
            #pragma unroll
            for (int dt = 0; dt < 4; ++dt) {
                bf16x8 vf = *reinterpret_cast<const bf16x8*>(&Vt[kt * 4 + l4][dt * 16 + l15][0]);
                oacc[dt] = __builtin_amdgcn_mfma_f32_16x16x32_bf16(pa, vf, oacc[dt], 0, 0, 0);
            }
        }
        #pragma unroll
        for (int dt = 0; dt < 4; ++dt)
            #pragma unroll
            for (int r = 0; r < 4; ++r)
                O[((size_t)(t0 + l4 * 4 + r) * 16 + n) * 1024 + hoff + dt * 16 + l15] = f2bf(oacc[dt][r]);
    }
}

// ---------------------------------------------------------------------------
// LayerNorm over D=1024, one wave per row; writes fp32 (and optional bf16 copy)
// ---------------------------------------------------------------------------
__global__ __launch_bounds__(256) void ln_kernel(
    const float* __restrict__ z, const float* __restrict__ g, const float* __restrict__ b,
    float* __restrict__ xf, unsigned short* __restrict__ xb)
{
    const int row  = blockIdx.x * 4 + (threadIdx.x >> 6);
    const int lane = threadIdx.x & 63;
    const float* zr = z + (size_t)row * 1024;
    f32x4 v[4];
    float s = 0.f;
    #pragma unroll
    for (int i = 0; i < 4; ++i) {
        v[i] = *reinterpret_cast<const f32x4*>(&zr[i * 256 + lane * 4]);
        s += v[i][0] + v[i][1] + v[i][2] + v[i][3];
    }
    #pragma unroll
    for (int dd = 1; dd < 64; dd <<= 1) s += __shfl_xor(s, dd, 64);
    const float mu = s * (1.f / 1024.f);
    float q = 0.f;
    #pragma unroll
    for (int i = 0; i < 4; ++i) {
        #pragma unroll
        for (int j = 0; j < 4; ++j) { const float d0 = v[i][j] - mu; q += d0 * d0; }
    }
    #pragma unroll
    for (int dd = 1; dd < 64; dd <<= 1) q += __shfl_xor(q, dd, 64);
    const float rstd = rsqrtf(q * (1.f / 1024.f) + 1e-5f);
    #pragma unroll
    for (int i = 0; i < 4; ++i) {
        const int col = i * 256 + lane * 4;
        f32x4 gg = *reinterpret_cast<const f32x4*>(&g[col]);
        f32x4 bb = *reinterpret_cast<const f32x4*>(&b[col]);
        f32x4 y;
        #pragma unroll
        for (int j = 0; j < 4; ++j) y[j] = (v[i][j] - mu) * rstd * gg[j] + bb[j];
        if (xf) *reinterpret_cast<f32x4*>(&xf[(size_t)row * 1024 + col]) = y;
        if (xb) {
            u16x4 pk;
            #pragma unroll
            for (int j = 0; j < 4; ++j) pk[j] = f2bf(y[j]);
            *reinterpret_cast<u16x4*>(&xb[(size_t)row * 1024 + col]) = pk;
        }
    }
}

__global__ __launch_bounds__(256) void cvt_bf16(
    const float* __restrict__ in, unsigned short* __restrict__ out, int n)
{
    const int i = (blockIdx.x * 256 + threadIdx.x) * 4;
    if (i >= n) return;
    f32x4 v = *reinterpret_cast<const f32x4*>(&in[i]);
    u16x4 pk;
    #pragma unroll
    for (int j = 0; j < 4; ++j) pk[j] = f2bf(v[j]);
    *reinterpret_cast<u16x4*>(&out[i]) = pk;
}

// ---------------------------------------------------------------------------
extern "C" void kernel_launch(void* const* d_in, const int* in_sizes, int n_in,
                              void* d_out, int out_size, void* d_ws, size_t ws_size,
                              hipStream_t stream)
{
    (void)in_sizes; (void)n_in; (void)out_size; (void)ws_size;
    const int M  = 4096;      // T*N = S*N
    const int Dm = 1024;
    const int FF = 4096;
    const size_t DD = (size_t)Dm * Dm;

    const float* tgt   = (const float*)d_in[0];
    const float* mem   = (const float*)d_in[1];
    const float* sa_wq = (const float*)d_in[2];
    const float* sa_wk = (const float*)d_in[3];
    const float* sa_wv = (const float*)d_in[4];
    const float* sa_wo = (const float*)d_in[5];
    const float* sa_bq = (const float*)d_in[6];
    const float* sa_bk = (const float*)d_in[7];
    const float* sa_bv = (const float*)d_in[8];
    const float* sa_bo = (const float*)d_in[9];
    const float* ca_wq = (const float*)d_in[10];
    const float* ca_wk = (const float*)d_in[11];
    const float* ca_wv = (const float*)d_in[12];
    const float* ca_wo = (const float*)d_in[13];
    const float* ca_bq = (const float*)d_in[14];
    const float* ca_bk = (const float*)d_in[15];
    const float* ca_bv = (const float*)d_in[16];
    const float* ca_bo = (const float*)d_in[17];
    const float* w1    = (const float*)d_in[18];
    const float* b1    = (const float*)d_in[19];
    const float* w2    = (const float*)d_in[20];
    const float* b2    = (const float*)d_in[21];
    const float* ln1g  = (const float*)d_in[22];
    const float* ln1b  = (const float*)d_in[23];
    const float* ln2g  = (const float*)d_in[24];
    const float* ln2b  = (const float*)d_in[25];
    const float* ln3g  = (const float*)d_in[26];
    const float* ln3b  = (const float*)d_in[27];
    const float* lnfg  = (const float*)d_in[28];
    const float* lnfb  = (const float*)d_in[29];

    // workspace: 67.1 MB total; z lives in d_out (fp32, same size as output)
    char* p = (char*)d_ws;
    float*          x_f   = (float*)p;          p += (size_t)M * Dm * 4;   // 16.78 MB
    unsigned short* x_b   = (unsigned short*)p; p += (size_t)M * Dm * 2;   //  8.39 MB
    unsigned short* mem_b = (unsigned short*)p; p += (size_t)M * Dm * 2;   //  8.39 MB
    unsigned short* q_b   = (unsigned short*)p; p += (size_t)M * Dm * 2;
    unsigned short* k_b   = (unsigned short*)p; p += (size_t)M * Dm * 2;
    unsigned short* v_b   = (unsigned short*)p; p += (size_t)M * Dm * 2;
    unsigned short* ao_b  = (unsigned short*)p; p += (size_t)M * Dm * 2;
    unsigned short* h_b   = q_b;  // FFN hidden [4096][4096] bf16 overlaps dead q/k/v/ao
    float*          z_f   = (float*)d_out;

    dim3 blk(256);
    auto gemm = [&](const unsigned short* A, const float* Bw, const float* bias,
                    const float* resid, unsigned short* ob, float* of,
                    int N, int K, float scale, int mode) {
        dim3 grid(N / 128, M / 128);
        gemm_bt<<<grid, blk, 0, stream>>>(A, Bw, bias, resid, ob, of, M, N, K, scale, mode);
    };

    cvt_bf16<<<4096, 256, 0, stream>>>(tgt, x_b, M * Dm);
    cvt_bf16<<<4096, 256, 0, stream>>>(mem, mem_b, M * Dm);

    const float* res = tgt;   // fp32 residual source
    for (int i = 0; i < 4; ++i) {
        // --- self-attention ---
        gemm(x_b, sa_wq + i * DD, sa_bq + i * Dm, nullptr, q_b, nullptr, Dm, Dm, 0.125f, 0);
        gemm(x_b, sa_wk + i * DD, sa_bk + i * Dm, nullptr, k_b, nullptr, Dm, Dm, 1.f, 0);
        gemm(x_b, sa_wv + i * DD, sa_bv + i * Dm, nullptr, v_b, nullptr, Dm, Dm, 1.f, 0);
        attn_fused<<<256, blk, 0, stream>>>(q_b, k_b, v_b, ao_b, 1);
        gemm(ao_b, sa_wo + i * DD, sa_bo + i * Dm, res, nullptr, z_f, Dm, Dm, 1.f, 2);
        ln_kernel<<<1024, blk, 0, stream>>>(z_f, ln1g + i * Dm, ln1b + i * Dm, x_f, x_b);
        res = x_f;
        // --- cross-attention ---
        gemm(x_b,   ca_wq + i * DD, ca_bq + i * Dm, nullptr, q_b, nullptr, Dm, Dm, 0.125f, 0);
        gemm(mem_b, ca_wk + i * DD, ca_bk + i * Dm, nullptr, k_b, nullptr, Dm, Dm, 1.f, 0);
        gemm(mem_b, ca_wv + i * DD, ca_bv + i * Dm, nullptr, v_b, nullptr, Dm, Dm, 1.f, 0);
        attn_fused<<<256, blk, 0, stream>>>(q_b, k_b, v_b, ao_b, 0);
        gemm(ao_b, ca_wo + i * DD, ca_bo + i * Dm, x_f, nullptr, z_f, Dm, Dm, 1.f, 2);
        ln_kernel<<<1024, blk, 0, stream>>>(z_f, ln2g + i * Dm, ln2b + i * Dm, x_f, x_b);
        // --- FFN ---
        gemm(x_b, w1 + (size_t)i * FF * Dm, b1 + i * FF, nullptr, h_b, nullptr, FF, Dm, 1.f, 1);
        gemm(h_b, w2 + (size_t)i * Dm * FF, b2 + i * Dm, x_f, nullptr, z_f, Dm, FF, 1.f, 2);
        ln_kernel<<<1024, blk, 0, stream>>>(z_f, ln3g + i * Dm, ln3b + i * Dm, x_f, x_b);
    }
    // final LayerNorm -> d_out (fp32)
    ln_kernel<<<1024, blk, 0, stream>>>(x_f, lnfg, lnfb, (float*)d_out, nullptr);
}

// Round 2
// 1854.663 us; speedup vs baseline: 1.5310x; 1.5310x over previous
//
#include <hip/hip_runtime.h>

// ---------------------------------------------------------------------------
// 4-layer transformer decoder, bf16 MFMA implementation (round 2).
// L=4, H=16, D=1024, FF=4096, T=S=256, N=16 -> M = 4096 rows.
// GEMM: m97 structure (128x128 tile, BK=32, global_load_lds width=16,
// single-buffer 2-barrier K-loop) + slot-XOR swizzle, all-bf16 operands.
// Weights fp32 -> bf16 packed once per layer (Q-scale 0.125 folded in).
// ---------------------------------------------------------------------------

typedef __attribute__((ext_vector_type(4))) float f32x4;
typedef __attribute__((ext_vector_type(8))) short bf16x8;
typedef __attribute__((ext_vector_type(4))) unsigned short u16x4;
typedef __attribute__((ext_vector_type(4))) unsigned int   u32x4;

__device__ __forceinline__ unsigned short f2bf(float f) {
    unsigned int u = __builtin_bit_cast(unsigned int, f);
    u += 0x7fffu + ((u >> 16) & 1u);   // RNE
    return (unsigned short)(u >> 16);
}

// global -> LDS direct copy, 16 B per lane. LDS dest = wave-uniform base +
// lane*16 (HW rule); global src is per-lane. CK-style addrspace casts.
__device__ __forceinline__ void gll16(const unsigned short* g, unsigned short* l) {
    auto* gp = reinterpret_cast<const __attribute__((address_space(1))) unsigned int*>(
        reinterpret_cast<uintptr_t>(g));
    auto* lp = reinterpret_cast<__attribute__((address_space(3))) unsigned int*>(
        reinterpret_cast<uintptr_t>(l));
    __builtin_amdgcn_global_load_lds(gp, lp, 16, 0, 0);
}

// ---------------------------------------------------------------------------
// GEMM: out = epilogue( A(bf16)[M][K] @ Bw(bf16)[N][K]^T + bias )
// mode 0: out_bf = bf16(acc+bias)
// mode 1: out_bf = bf16(relu(acc+bias))
// mode 2: out_f  = acc + bias + resid
// LDS tile [128][32] bf16 (64 B rows), 16B slots XOR-swizzled: the data for
// k-chunk c of row r lives at slot c^(r&3). global_load_lds writes linearly,
// so the SOURCE address is pre-swizzled (rule #21) and ds_read applies the
// same XOR. Spreads the 16-consecutive-row b128 fragment reads over all banks.
// ---------------------------------------------------------------------------
__global__ __launch_bounds__(256) void gemm_bt(
    const unsigned short* __restrict__ A,
    const unsigned short* __restrict__ Bw,
    const float* __restrict__ bias,
    const float* __restrict__ resid,
    unsigned short* __restrict__ outb,
    float* __restrict__ outf,
    int M, int N, int K, int mode)
{
    __shared__ unsigned short Al[128 * 32];
    __shared__ unsigned short Bl[128 * 32];
    const int tid  = threadIdx.x;
    const int lane = tid & 63;
    const int w    = tid >> 6;
    const int wr   = (w >> 1) * 64;
    const int wc   = (w & 1) * 64;
    const int m0   = blockIdx.y * 128;
    const int n0   = blockIdx.x * 128;
    const int l15  = lane & 15;
    const int l4   = lane >> 4;

    // staging: round j (j=0,1), wave w covers rows j*64 + w*16 + (lane>>2);
    // lane's 16B chunk lands at LDS slot (lane&3) of its row, so the global
    // column is the pre-swizzled slot ((lane&3) ^ (row&3)).
    const int srow = (lane >> 2);                       // 0..15 within 16-row group
    const int scol = ((lane & 3) ^ (srow & 3)) * 8;     // swizzled k-chunk (elems)
    const unsigned short* ag = A  + (size_t)(m0 + w * 16 + srow) * K + scol;
    const unsigned short* bg = Bw + (size_t)(n0 + w * 16 + srow) * K + scol;
    unsigned short* al = &Al[(w * 16) * 32];
    unsigned short* bl = &Bl[(w * 16) * 32];
    const size_t jstepA = (size_t)64 * K;

    // fragment read offsets (swizzled): row r, k-chunk l4 -> slot l4^(r&3)
    int aoff[4], boff[4];
    #pragma unroll
    for (int i = 0; i < 4; ++i) {
        const int ra = wr + i * 16 + l15;
        const int rb = wc + i * 16 + l15;
        aoff[i] = ra * 32 + ((l4 ^ (ra & 3)) * 8);
        boff[i] = rb * 32 + ((l4 ^ (rb & 3)) * 8);
    }

    f32x4 acc[4][4];
    #pragma unroll
    for (int mi = 0; mi < 4; ++mi)
        #pragma unroll
        for (int ni = 0; ni < 4; ++ni)
            acc[mi][ni] = (f32x4){0.f, 0.f, 0.f, 0.f};

    for (int k0 = 0; k0 < K; k0 += 32) {
        #pragma unroll
        for (int j = 0; j < 2; ++j) {
            gll16(ag + j * jstepA, al + j * 64 * 32);
            gll16(bg + j * jstepA, bl + j * 64 * 32);
        }
        __syncthreads();

        bf16x8 af[4], bf[4];
        #pragma unroll
        for (int i = 0; i < 4; ++i) af[i] = *reinterpret_cast<const bf16x8*>(&Al[aoff[i]]);
        #pragma unroll
        for (int i = 0; i < 4; ++i) bf[i] = *reinterpret_cast<const bf16x8*>(&Bl[boff[i]]);
        #pragma unroll
        for (int mi = 0; mi < 4; ++mi)
            #pragma unroll
            for (int ni = 0; ni < 4; ++ni)
                acc[mi][ni] = __builtin_amdgcn_mfma_f32_16x16x32_bf16(af[mi], bf[ni], acc[mi][ni], 0, 0, 0);
        __syncthreads();
        ag += 32; bg += 32;
    }

    // epilogue: C/D layout col = lane&15, row = (lane>>4)*4 + r
    #pragma unroll
    for (int mi = 0; mi < 4; ++mi) {
        #pragma unroll
        for (int ni = 0; ni < 4; ++ni) {
            const int col = n0 + wc + ni * 16 + l15;
            const float bs = bias[col];
            #pragma unroll
            for (int r = 0; r < 4; ++r) {
                const int row = m0 + wr + mi * 16 + l4 * 4 + r;
                const float val = acc[mi][ni][r] + bs;
                if (mode == 0)      outb[(size_t)row * N + col] = f2bf(val);
                else if (mode == 1) outb[(size_t)row * N + col] = f2bf(fmaxf(val, 0.f));
                else                outf[(size_t)row * N + col] = val + resid[(size_t)row * N + col];
            }
        }
    }
}

// ---------------------------------------------------------------------------
// Fused attention: one workgroup per (n,h). T=S=256, hd=64.
// Q pre-scaled (0.125 folded into packed weights). Strides parameterized so
// Q/K/V can live in fused projection buffers.
// ---------------------------------------------------------------------------
__global__ __launch_bounds__(256) void attn_fused(
    const unsigned short* __restrict__ Q, int qs,
    const unsigned short* __restrict__ Kb, int ks_,
    const unsigned short* __restrict__ Vb, int vs,
    unsigned short* __restrict__ O,
    int causal)
{
    __shared__ unsigned short Kl[8][256][8];        // 32 KB
    __shared__ unsigned short Vt[32][64][8];        // 32 KB
    __shared__ unsigned short Pl[4][32][16][8];     // 32 KB
    const int tid  = threadIdx.x;
    const int lane = tid & 63;
    const int w    = tid >> 6;
    const int n    = blockIdx.x >> 4;
    const int h    = blockIdx.x & 15;
    const int l15  = lane & 15;
    const int l4   = lane >> 4;
    const size_t hoff = (size_t)h * 64;

    #pragma unroll
    for (int i = 0; i < 8; ++i) {
        const int e = i * 256 + tid;
        const int s = e >> 3;
        const int c = e & 7;
        u32x4 kv = *reinterpret_cast<const u32x4*>(&Kb[((size_t)s * 16 + n) * ks_ + hoff + c * 8]);
        *reinterpret_cast<u32x4*>(&Kl[c][s][0]) = kv;
        u32x4 vv = *reinterpret_cast<const u32x4*>(&Vb[((size_t)s * 16 + n) * vs + hoff + c * 8]);
        const unsigned short* ve = reinterpret_cast<const unsigned short*>(&vv);
        #pragma unroll
        for (int j = 0; j < 8; ++j)
            Vt[s >> 3][c * 8 + j][s & 7] = ve[j];
    }
    __syncthreads();

    for (int ch = 0; ch < 4; ++ch) {
        const int t0 = w * 64 + ch * 16;
        bf16x8 qa[2];
        #pragma unroll
        for (int ks = 0; ks < 2; ++ks)
            qa[ks] = *reinterpret_cast<const bf16x8*>(
                &Q[((size_t)(t0 + l15) * 16 + n) * qs + hoff + ks * 32 + l4 * 8]);

        f32x4 sc[16];
        #pragma unroll
        for (int st = 0; st < 16; ++st) {
            f32x4 a = (f32x4){0.f, 0.f, 0.f, 0.f};
            #pragma unroll
            for (int ks = 0; ks < 2; ++ks) {
                bf16x8 kf = *reinterpret_cast<const bf16x8*>(&Kl[ks * 4 + l4][st * 16 + l15][0]);
                a = __builtin_amdgcn_mfma_f32_16x16x32_bf16(qa[ks], kf, a, 0, 0, 0);
            }
            sc[st] = a;
        }
        if (causal) {
            #pragma unroll
            for (int st = 0; st < 16; ++st) {
                const int sg = st * 16 + l15;
                #pragma unroll
                for (int r = 0; r < 4; ++r) {
                    const int tg = t0 + l4 * 4 + r;
                    if (sg > tg) sc[st][r] += -1e9f;
                }
            }
        }
        #pragma unroll
        for (int r = 0; r < 4; ++r) {
            float mx = -3.0e38f;
            #pragma unroll
            for (int st = 0; st < 16; ++st) mx = fmaxf(mx, sc[st][r]);
            #pragma unroll
            for (int dd = 1; dd < 16; dd <<= 1) mx = fmaxf(mx, __shfl_xor(mx, dd, 64));
            float sum = 0.f;
            #pragma unroll
            for (int st = 0; st < 16; ++st) {
                const float e = __expf(sc[st][r] - mx);
                sc[st][r] = e;
                sum += e;
            }
            #pragma unroll
            for (int dd = 1; dd < 16; dd <<= 1) sum += __shfl_xor(sum, dd, 64);
            const float inv = 1.f / sum;
            const int rl = l4 * 4 + r;
            #pragma unroll
            for (int st = 0; st < 16; ++st) {
                const int sg = st * 16 + l15;
                Pl[w][sg >> 3][rl][sg & 7] = f2bf(sc[st][r] * inv);
            }
        }
        f32x4 oacc[4];
        #pragma unroll
        for (int dt = 0; dt < 4; ++dt) oacc[dt] = (f32x4){0.f, 0.f, 0.f, 0.f};
        #pragma unroll
        for (int kt = 0; kt < 8; ++kt) {
            bf16x8 pa = *reinterpret_cast<const bf16x8*>(&Pl[w][kt * 4 + l4][l15][0]);
            #pragma unroll
            for (int dt = 0; dt < 4; ++dt) {
                bf16x8 vf = *reinterpret_cast<const bf16x8*>(&Vt[kt * 4 + l4][dt * 16 + l15][0]);
                oacc[dt] = __builtin_amdgcn_mfma_f32_16x16x32_bf16(pa, vf, oacc[dt], 0, 0, 0);
            }
        }
        #pragma unroll
        for (int dt = 0; dt < 4; ++dt)
            #pragma unroll
            for (int r = 0; r < 4; ++r)
                O[((size_t)(t0 + l4 * 4 + r) * 16 + n) * 1024 + hoff + dt * 16 + l15] = f2bf(oacc[dt][r]);
    }
}

// ---------------------------------------------------------------------------
// LayerNorm over D=1024, one wave per row; writes fp32 (and optional bf16 copy)
// ---------------------------------------------------------------------------
__global__ __launch_bounds__(256) void ln_kernel(
    const float* __restrict__ z, const float* __restrict__ g, const float* __restrict__ b,
    float* __restrict__ xf, unsigned short* __restrict__ xb)
{
    const int row  = blockIdx.x * 4 + (threadIdx.x >> 6);
    const int lane = threadIdx.x & 63;
    const float* zr = z + (size_t)row * 1024;
    f32x4 v[4];
    float s = 0.f;
    #pragma unroll
    for (int i = 0; i < 4; ++i) {
        v[i] = *reinterpret_cast<const f32x4*>(&zr[i * 256 + lane * 4]);
        s += v[i][0] + v[i][1] + v[i][2] + v[i][3];
    }
    #pragma unroll
    for (int dd = 1; dd < 64; dd <<= 1) s += __shfl_xor(s, dd, 64);
    const float mu = s * (1.f / 1024.f);
    float q = 0.f;
    #pragma unroll
    for (int i = 0; i < 4; ++i) {
        #pragma unroll
        for (int j = 0; j < 4; ++j) { const float d0 = v[i][j] - mu; q += d0 * d0; }
    }
    #pragma unroll
    for (int dd = 1; dd < 64; dd <<= 1) q += __shfl_xor(q, dd, 64);
    const float rstd = rsqrtf(q * (1.f / 1024.f) + 1e-5f);
    #pragma unroll
    for (int i = 0; i < 4; ++i) {
        const int col = i * 256 + lane * 4;
        f32x4 gg = *reinterpret_cast<const f32x4*>(&g[col]);
        f32x4 bb = *reinterpret_cast<const f32x4*>(&b[col]);
        f32x4 y;
        #pragma unroll
        for (int j = 0; j < 4; ++j) y[j] = (v[i][j] - mu) * rstd * gg[j] + bb[j];
        if (xf) *reinterpret_cast<f32x4*>(&xf[(size_t)row * 1024 + col]) = y;
        if (xb) {
            u16x4 pk;
            #pragma unroll
            for (int j = 0; j < 4; ++j) pk[j] = f2bf(y[j]);
            *reinterpret_cast<u16x4*>(&xb[(size_t)row * 1024 + col]) = pk;
        }
    }
}

__global__ __launch_bounds__(256) void cvt_bf16(
    const float* __restrict__ in, unsigned short* __restrict__ out, int n)
{
    const int i = (blockIdx.x * 256 + threadIdx.x) * 4;
    if (i >= n) return;
    f32x4 v = *reinterpret_cast<const f32x4*>(&in[i]);
    u16x4 pk;
    #pragma unroll
    for (int j = 0; j < 4; ++j) pk[j] = f2bf(v[j]);
    *reinterpret_cast<u16x4*>(&out[i]) = pk;
}

// ---------------------------------------------------------------------------
// Per-layer weight pack: fp32 -> bf16, Q parts scaled by 0.125 (exact: pure
// exponent shift). Dest layout (elements, DD = 1024*1024):
//   [0,3DD)  sa qkv   [3DD,6DD) ca qkv   [6DD,7DD) sa_wo   [7DD,8DD) ca_wo
//   [8DD,12DD) w1     [12DD,16DD) w2
// ---------------------------------------------------------------------------
__global__ __launch_bounds__(256) void pack_layer_w(
    const float* __restrict__ sa_wq, const float* __restrict__ sa_wk, const float* __restrict__ sa_wv,
    const float* __restrict__ ca_wq, const float* __restrict__ ca_wk, const float* __restrict__ ca_wv,
    const float* __restrict__ sa_wo, const float* __restrict__ ca_wo,
    const float* __restrict__ w1,   const float* __restrict__ w2,
    unsigned short* __restrict__ dst, int layer)
{
    const size_t DD = 1024u * 1024u;
    const size_t e  = ((size_t)blockIdx.x * 256 + threadIdx.x) * 4;
    const float* src;
    float scale = 1.f;
    if (e < 3 * DD) {
        const int part = (int)(e / DD);
        src = (part == 0 ? sa_wq : part == 1 ? sa_wk : sa_wv) + layer * DD + (e % DD);
        if (part == 0) scale = 0.125f;
    } else if (e < 6 * DD) {
        const size_t r = e - 3 * DD;
        const int part = (int)(r / DD);
        src = (part == 0 ? ca_wq : part == 1 ? ca_wk : ca_wv) + layer * DD + (r % DD);
        if (part == 0) scale = 0.125f;
    } else if (e < 7 * DD)  { src = sa_wo + layer * DD + (e - 6 * DD); }
    else if (e < 8 * DD)    { src = ca_wo + layer * DD + (e - 7 * DD); }
    else if (e < 12 * DD)   { src = w1 + (size_t)layer * 4 * DD + (e - 8 * DD); }
    else                    { src = w2 + (size_t)layer * 4 * DD + (e - 12 * DD); }
    f32x4 v = *reinterpret_cast<const f32x4*>(src);
    u16x4 pk;
    #pragma unroll
    for (int j = 0; j < 4; ++j) pk[j] = f2bf(v[j] * scale);
    *reinterpret_cast<u16x4*>(&dst[e]) = pk;
}

// Packed fp32 biases: {sa,ca}[l][3072] = [bq*0.125 | bk | bv]
__global__ __launch_bounds__(256) void pack_bias(
    const float* __restrict__ sa_bq, const float* __restrict__ sa_bk, const float* __restrict__ sa_bv,
    const float* __restrict__ ca_bq, const float* __restrict__ ca_bk, const float* __restrict__ ca_bv,
    float* __restrict__ sab, float* __restrict__ cab)
{
    const int idx = blockIdx.x * 256 + threadIdx.x;          // < 24576
    const int half = idx / 12288;
    const int r    = idx % 12288;
    const int l    = r / 3072;
    const int pc   = r % 3072;
    const int part = pc >> 10;
    const int c    = pc & 1023;
    const float* src = half == 0 ? (part == 0 ? sa_bq : part == 1 ? sa_bk : sa_bv)
                                 : (part == 0 ? ca_bq : part == 1 ? ca_bk : ca_bv);
    const float v = src[l * 1024 + c] * (part == 0 ? 0.125f : 1.f);
    (half ? cab : sab)[l * 3072 + pc] = v;
}

// ---------------------------------------------------------------------------
extern "C" void kernel_launch(void* const* d_in, const int* in_sizes, int n_in,
                              void* d_out, int out_size, void* d_ws, size_t ws_size,
                              hipStream_t stream)
{
    (void)in_sizes; (void)n_in; (void)out_size; (void)ws_size;
    const int M  = 4096;
    const int Dm = 1024;
    const size_t DD = (size_t)Dm * Dm;

    const float* tgt   = (const float*)d_in[0];
    const float* mem   = (const float*)d_in[1];
    const float* sa_wq = (const float*)d_in[2];
    const float* sa_wk = (const float*)d_in[3];
    const float* sa_wv = (const float*)d_in[4];
    const float* sa_wo = (const float*)d_in[5];
    const float* sa_bq = (const float*)d_in[6];
    const float* sa_bk = (const float*)d_in[7];
    const float* sa_bv = (const float*)d_in[8];
    const float* sa_bo = (const float*)d_in[9];
    const float* ca_wq = (const float*)d_in[10];
    const float* ca_wk = (const float*)d_in[11];
    const float* ca_wv = (const float*)d_in[12];
    const float* ca_wo = (const float*)d_in[13];
    const float* ca_bq = (const float*)d_in[14];
    const float* ca_bk = (const float*)d_in[15];
    const float* ca_bv = (const float*)d_in[16];
    const float* ca_bo = (const float*)d_in[17];
    const float* w1    = (const float*)d_in[18];
    const float* b1    = (const float*)d_in[19];
    const float* w2    = (const float*)d_in[20];
    const float* b2    = (const float*)d_in[21];
    const float* ln1g  = (const float*)d_in[22];
    const float* ln1b  = (const float*)d_in[23];
    const float* ln2g  = (const float*)d_in[24];
    const float* ln2b  = (const float*)d_in[25];
    const float* ln3g  = (const float*)d_in[26];
    const float* ln3b  = (const float*)d_in[27];
    const float* lnfg  = (const float*)d_in[28];
    const float* lnfb  = (const float*)d_in[29];

    // workspace layout (~126 MB)
    char* p = (char*)d_ws;
    float*          x_f    = (float*)p;          p += (size_t)M * Dm * 4;       // 16.78 MB
    unsigned short* x_b    = (unsigned short*)p; p += (size_t)M * Dm * 2;       //  8.39 MB
    unsigned short* mem_b  = (unsigned short*)p; p += (size_t)M * Dm * 2;       //  8.39 MB
    unsigned short* qkv_b  = (unsigned short*)p; p += (size_t)M * 3072 * 2;     // 25.17 MB
    unsigned short* caq_b  = (unsigned short*)p; p += (size_t)M * Dm * 2;       //  8.39 MB
    unsigned short* cakv_b = (unsigned short*)p; p += (size_t)M * 2048 * 2;     // 16.78 MB
    unsigned short* ao_b   = (unsigned short*)p; p += (size_t)M * Dm * 2;       //  8.39 MB
    unsigned short* wpack  = (unsigned short*)p; p += 16 * DD * 2;              // 33.55 MB
    float*          sab    = (float*)p;          p += 4 * 3072 * 4;
    float*          cab    = (float*)p;          p += 4 * 3072 * 4;
    unsigned short* h_b    = qkv_b;   // FFN hidden [4096][4096] bf16 overlaps qkv+caq
    float*          z_f    = (float*)d_out;

    dim3 blk(256);
    auto gemm = [&](const unsigned short* A, const unsigned short* Bw, const float* bias,
                    const float* resid, unsigned short* ob, float* of, int N, int K, int mode) {
        dim3 grid(N / 128, M / 128);
        gemm_bt<<<grid, blk, 0, stream>>>(A, Bw, bias, resid, ob, of, M, N, K, mode);
    };

    cvt_bf16<<<4096, blk, 0, stream>>>(tgt, x_b, M * Dm);
    cvt_bf16<<<4096, blk, 0, stream>>>(mem, mem_b, M * Dm);
    pack_bias<<<96, blk, 0, stream>>>(sa_bq, sa_bk, sa_bv, ca_bq, ca_bk, ca_bv, sab, cab);

    const float* res = tgt;
    for (int i = 0; i < 4; ++i) {
        pack_layer_w<<<16384, blk, 0, stream>>>(sa_wq, sa_wk, sa_wv, ca_wq, ca_wk, ca_wv,
                                                sa_wo, ca_wo, w1, w2, wpack, i);
        // --- self-attention (fused QKV, N=3072) ---
        gemm(x_b, wpack, sab + i * 3072, nullptr, qkv_b, nullptr, 3072, 1024, 0);
        attn_fused<<<256, blk, 0, stream>>>(qkv_b, 3072, qkv_b + 1024, 3072, qkv_b + 2048, 3072, ao_b, 1);
        gemm(ao_b, wpack + 6 * DD, sa_bo + i * Dm, res, nullptr, z_f, 1024, 1024, 2);
        ln_kernel<<<1024, blk, 0, stream>>>(z_f, ln1g + i * Dm, ln1b + i * Dm, x_f, x_b);
        res = x_f;
        // --- cross-attention (Q from x; fused KV from memory, N=2048) ---
        gemm(x_b,   wpack + 3 * DD, cab + i * 3072,        nullptr, caq_b,  nullptr, 1024, 1024, 0);
        gemm(mem_b, wpack + 4 * DD, cab + i * 3072 + 1024, nullptr, cakv_b, nullptr, 2048, 1024, 0);
        attn_fused<<<256, blk, 0, stream>>>(caq_b, 1024, cakv_b, 2048, cakv_b + 1024, 2048, ao_b, 0);
        gemm(ao_b, wpack + 7 * DD, ca_bo + i * Dm, x_f, nullptr, z_f, 1024, 1024, 2);
        ln_kernel<<<1024, blk, 0, stream>>>(z_f, ln2g + i * Dm, ln2b + i * Dm, x_f, x_b);
        // --- FFN ---
        gemm(x_b, wpack + 8 * DD,  b1 + i * 4096, nullptr, h_b, nullptr, 4096, 1024, 1);
        gemm(h_b, wpack + 12 * DD, b2 + i * Dm,   x_f, nullptr, z_f, 1024, 4096, 2);
        ln_kernel<<<1024, blk, 0, stream>>>(z_f, ln3g + i * Dm, ln3b + i * Dm, x_f, x_b);
    }
    ln_kernel<<<1024, blk, 0, stream>>>(x_f, lnfg, lnfb, (float*)d_out, nullptr);
}

// Round 3
// 1592.614 us; speedup vs baseline: 1.7829x; 1.1645x over previous
//
#include <hip/hip_runtime.h>

// ---------------------------------------------------------------------------
// 4-layer transformer decoder, bf16 MFMA implementation (round 3).
// GEMM: 128x128 tile, BK=32, global_load_lds width=16, DOUBLE-BUFFERED
// 2-phase K-loop (stage next || compute cur, one barrier/K-step) +
// XCD-aware band swizzle + slot-XOR LDS swizzle. All-bf16 operands,
// weights packed once per layer (Q-scale folded).
// ---------------------------------------------------------------------------

typedef __attribute__((ext_vector_type(4))) float f32x4;
typedef __attribute__((ext_vector_type(8))) short bf16x8;
typedef __attribute__((ext_vector_type(4))) unsigned short u16x4;
typedef __attribute__((ext_vector_type(4))) unsigned int   u32x4;

__device__ __forceinline__ unsigned short f2bf(float f) {
    unsigned int u = __builtin_bit_cast(unsigned int, f);
    u += 0x7fffu + ((u >> 16) & 1u);   // RNE
    return (unsigned short)(u >> 16);
}

__device__ __forceinline__ void gll16(const unsigned short* g, unsigned short* l) {
    auto* gp = reinterpret_cast<const __attribute__((address_space(1))) unsigned int*>(
        reinterpret_cast<uintptr_t>(g));
    auto* lp = reinterpret_cast<__attribute__((address_space(3))) unsigned int*>(
        reinterpret_cast<uintptr_t>(l));
    __builtin_amdgcn_global_load_lds(gp, lp, 16, 0, 0);
}

// ---------------------------------------------------------------------------
// GEMM: out = epilogue( A(bf16)[M][K] @ Bw(bf16)[N][K]^T + bias )
// mode 0: bf16(acc+bias)   mode 1: bf16(relu(acc+bias))   mode 2: f32 +resid
// ---------------------------------------------------------------------------
__global__ __launch_bounds__(256) void gemm_bt(
    const unsigned short* __restrict__ A,
    const unsigned short* __restrict__ Bw,
    const float* __restrict__ bias,
    const float* __restrict__ resid,
    unsigned short* __restrict__ outb,
    float* __restrict__ outf,
    int M, int N, int K, int mode)
{
    __shared__ unsigned short Al[2][128 * 32];
    __shared__ unsigned short Bl[2][128 * 32];
    const int tid  = threadIdx.x;
    const int lane = tid & 63;
    const int w    = tid >> 6;
    const int wr   = (w >> 1) * 64;
    const int wc   = (w & 1) * 64;
    const int l15  = lane & 15;
    const int l4   = lane >> 4;

    // XCD-aware band swizzle: each XCD owns a gy/8-row band, traversed
    // column-major (concurrent working set ~4 A-panels + B stream -> L2-fits).
    const int gx = gridDim.x, gy = gridDim.y;
    const int orig = blockIdx.y * gx + blockIdx.x;
    const int xcd  = orig & 7;
    const int lin  = orig >> 3;
    const int rpb  = gy >> 3;                  // gy == 32 for all our GEMMs
    const int m0   = (xcd * rpb + (lin % rpb)) * 128;
    const int n0   = (lin / rpb) * 128;

    // staging: wave w covers rows [w*16, w*16+16) (+64 for j=1); lane's 16B
    // chunk lands at slot (lane&3), so global col is pre-swizzled slot^(row&3).
    const int srow = lane >> 2;
    const int scol = ((lane & 3) ^ (srow & 3)) * 8;
    const unsigned short* ag = A  + (size_t)(m0 + w * 16 + srow) * K + scol;
    const unsigned short* bg = Bw + (size_t)(n0 + w * 16 + srow) * K + scol;
    const size_t jstep = (size_t)64 * K;
    const int lbase = (w * 16) * 32;

    // fragment read offsets (swizzled): row r, k-chunk l4 -> slot l4^(r&3)
    int aoff[4], boff[4];
    #pragma unroll
    for (int i = 0; i < 4; ++i) {
        const int ra = wr + i * 16 + l15;
        const int rb = wc + i * 16 + l15;
        aoff[i] = ra * 32 + ((l4 ^ (ra & 3)) * 8);
        boff[i] = rb * 32 + ((l4 ^ (rb & 3)) * 8);
    }

    f32x4 acc[4][4];
    #pragma unroll
    for (int mi = 0; mi < 4; ++mi)
        #pragma unroll
        for (int ni = 0; ni < 4; ++ni)
            acc[mi][ni] = (f32x4){0.f, 0.f, 0.f, 0.f};

    // prologue: stage tile 0 into buf 0
    #pragma unroll
    for (int j = 0; j < 2; ++j) {
        gll16(ag + j * jstep, &Al[0][lbase + j * 64 * 32]);
        gll16(bg + j * jstep, &Bl[0][lbase + j * 64 * 32]);
    }
    __syncthreads();

    const int nt = K >> 5;
    int cur = 0;
    for (int t = 0; t < nt; ++t) {
        if (t + 1 < nt) {                      // issue next-tile loads FIRST
            ag += 32; bg += 32;
            #pragma unroll
            for (int j = 0; j < 2; ++j) {
                gll16(ag + j * jstep, &Al[cur ^ 1][lbase + j * 64 * 32]);
                gll16(bg + j * jstep, &Bl[cur ^ 1][lbase + j * 64 * 32]);
            }
        }
        const unsigned short* ac = &Al[cur][0];
        const unsigned short* bc = &Bl[cur][0];
        bf16x8 af[4], bf[4];
        #pragma unroll
        for (int i = 0; i < 4; ++i) af[i] = *reinterpret_cast<const bf16x8*>(&ac[aoff[i]]);
        #pragma unroll
        for (int i = 0; i < 4; ++i) bf[i] = *reinterpret_cast<const bf16x8*>(&bc[boff[i]]);
        #pragma unroll
        for (int mi = 0; mi < 4; ++mi)
            #pragma unroll
            for (int ni = 0; ni < 4; ++ni)
                acc[mi][ni] = __builtin_amdgcn_mfma_f32_16x16x32_bf16(af[mi], bf[ni], acc[mi][ni], 0, 0, 0);
        __syncthreads();                       // drains vmcnt: next buf ready
        cur ^= 1;
    }

    // epilogue: C/D layout col = lane&15, row = (lane>>4)*4 + r
    #pragma unroll
    for (int mi = 0; mi < 4; ++mi) {
        #pragma unroll
        for (int ni = 0; ni < 4; ++ni) {
            const int col = n0 + wc + ni * 16 + l15;
            const float bs = bias[col];
            #pragma unroll
            for (int r = 0; r < 4; ++r) {
                const int row = m0 + wr + mi * 16 + l4 * 4 + r;
                const float val = acc[mi][ni][r] + bs;
                if (mode == 0)      outb[(size_t)row * N + col] = f2bf(val);
                else if (mode == 1) outb[(size_t)row * N + col] = f2bf(fmaxf(val, 0.f));
                else                outf[(size_t)row * N + col] = val + resid[(size_t)row * N + col];
            }
        }
    }
}

// ---------------------------------------------------------------------------
// Fused attention: one workgroup per (n,h). T=S=256, hd=64.
// ---------------------------------------------------------------------------
__global__ __launch_bounds__(256) void attn_fused(
    const unsigned short* __restrict__ Q, int qs,
    const unsigned short* __restrict__ Kb, int ks_,
    const unsigned short* __restrict__ Vb, int vs,
    unsigned short* __restrict__ O,
    int causal)
{
    __shared__ unsigned short Kl[8][256][8];
    __shared__ unsigned short Vt[32][64][8];
    __shared__ unsigned short Pl[4][32][16][8];
    const int tid  = threadIdx.x;
    const int lane = tid & 63;
    const int w    = tid >> 6;
    const int n    = blockIdx.x >> 4;
    const int h    = blockIdx.x & 15;
    const int l15  = lane & 15;
    const int l4   = lane >> 4;
    const size_t hoff = (size_t)h * 64;

    #pragma unroll
    for (int i = 0; i < 8; ++i) {
        const int e = i * 256 + tid;
        const int s = e >> 3;
        const int c = e & 7;
        u32x4 kv = *reinterpret_cast<const u32x4*>(&Kb[((size_t)s * 16 + n) * ks_ + hoff + c * 8]);
        *reinterpret_cast<u32x4*>(&Kl[c][s][0]) = kv;
        u32x4 vv = *reinterpret_cast<const u32x4*>(&Vb[((size_t)s * 16 + n) * vs + hoff + c * 8]);
        const unsigned short* ve = reinterpret_cast<const unsigned short*>(&vv);
        #pragma unroll
        for (int j = 0; j < 8; ++j)
            Vt[s >> 3][c * 8 + j][s & 7] = ve[j];
    }
    __syncthreads();

    for (int ch = 0; ch < 4; ++ch) {
        const int t0 = w * 64 + ch * 16;
        bf16x8 qa[2];
        #pragma unroll
        for (int ks = 0; ks < 2; ++ks)
            qa[ks] = *reinterpret_cast<const bf16x8*>(
                &Q[((size_t)(t0 + l15) * 16 + n) * qs + hoff + ks * 32 + l4 * 8]);

        f32x4 sc[16];
        #pragma unroll
        for (int st = 0; st < 16; ++st) {
            f32x4 a = (f32x4){0.f, 0.f, 0.f, 0.f};
            #pragma unroll
            for (int ks = 0; ks < 2; ++ks) {
                bf16x8 kf = *reinterpret_cast<const bf16x8*>(&Kl[ks * 4 + l4][st * 16 + l15][0]);
                a = __builtin_amdgcn_mfma_f32_16x16x32_bf16(qa[ks], kf, a, 0, 0, 0);
            }
            sc[st] = a;
        }
        if (causal) {
            #pragma unroll
            for (int st = 0; st < 16; ++st) {
                const int sg = st * 16 + l15;
                #pragma unroll
                for (int r = 0; r < 4; ++r) {
                    const int tg = t0 + l4 * 4 + r;
                    if (sg > tg) sc[st][r] += -1e9f;
                }
            }
        }
        #pragma unroll
        for (int r = 0; r < 4; ++r) {
            float mx = -3.0e38f;
            #pragma unroll
            for (int st = 0; st < 16; ++st) mx = fmaxf(mx, sc[st][r]);
            #pragma unroll
            for (int dd = 1; dd < 16; dd <<= 1) mx = fmaxf(mx, __shfl_xor(mx, dd, 64));
            float sum = 0.f;
            #pragma unroll
            for (int st = 0; st < 16; ++st) {
                const float e = __expf(sc[st][r] - mx);
                sc[st][r] = e;
                sum += e;
            }
            #pragma unroll
            for (int dd = 1; dd < 16; dd <<= 1) sum += __shfl_xor(sum, dd, 64);
            const float inv = 1.f / sum;
            const int rl = l4 * 4 + r;
            #pragma unroll
            for (int st = 0; st < 16; ++st) {
                const int sg = st * 16 + l15;
                Pl[w][sg >> 3][rl][sg & 7] = f2bf(sc[st][r] * inv);
            }
        }
        f32x4 oacc[4];
        #pragma unroll
        for (int dt = 0; dt < 4; ++dt) oacc[dt] = (f32x4){0.f, 0.f, 0.f, 0.f};
        #pragma unroll
        for (int kt = 0; kt < 8; ++kt) {
            bf16x8 pa = *reinterpret_cast<const bf16x8*>(&Pl[w][kt * 4 + l4][l15][0]);
            #pragma unroll
            for (int dt = 0; dt < 4; ++dt) {
                bf16x8 vf = *reinterpret_cast<const bf16x8*>(&Vt[kt * 4 + l4][dt * 16 + l15][0]);
                oacc[dt] = __builtin_amdgcn_mfma_f32_16x16x32_bf16(pa, vf, oacc[dt], 0, 0, 0);
            }
        }
        #pragma unroll
        for (int dt = 0; dt < 4; ++dt)
            #pragma unroll
            for (int r = 0; r < 4; ++r)
                O[((size_t)(t0 + l4 * 4 + r) * 16 + n) * 1024 + hoff + dt * 16 + l15] = f2bf(oacc[dt][r]);
    }
}

// ---------------------------------------------------------------------------
__global__ __launch_bounds__(256) void ln_kernel(
    const float* __restrict__ z, const float* __restrict__ g, const float* __restrict__ b,
    float* __restrict__ xf, unsigned short* __restrict__ xb)
{
    const int row  = blockIdx.x * 4 + (threadIdx.x >> 6);
    const int lane = threadIdx.x & 63;
    const float* zr = z + (size_t)row * 1024;
    f32x4 v[4];
    float s = 0.f;
    #pragma unroll
    for (int i = 0; i < 4; ++i) {
        v[i] = *reinterpret_cast<const f32x4*>(&zr[i * 256 + lane * 4]);
        s += v[i][0] + v[i][1] + v[i][2] + v[i][3];
    }
    #pragma unroll
    for (int dd = 1; dd < 64; dd <<= 1) s += __shfl_xor(s, dd, 64);
    const float mu = s * (1.f / 1024.f);
    float q = 0.f;
    #pragma unroll
    for (int i = 0; i < 4; ++i) {
        #pragma unroll
        for (int j = 0; j < 4; ++j) { const float d0 = v[i][j] - mu; q += d0 * d0; }
    }
    #pragma unroll
    for (int dd = 1; dd < 64; dd <<= 1) q += __shfl_xor(q, dd, 64);
    const float rstd = rsqrtf(q * (1.f / 1024.f) + 1e-5f);
    #pragma unroll
    for (int i = 0; i < 4; ++i) {
        const int col = i * 256 + lane * 4;
        f32x4 gg = *reinterpret_cast<const f32x4*>(&g[col]);
        f32x4 bb = *reinterpret_cast<const f32x4*>(&b[col]);
        f32x4 y;
        #pragma unroll
        for (int j = 0; j < 4; ++j) y[j] = (v[i][j] - mu) * rstd * gg[j] + bb[j];
        if (xf) *reinterpret_cast<f32x4*>(&xf[(size_t)row * 1024 + col]) = y;
        if (xb) {
            u16x4 pk;
            #pragma unroll
            for (int j = 0; j < 4; ++j) pk[j] = f2bf(y[j]);
            *reinterpret_cast<u16x4*>(&xb[(size_t)row * 1024 + col]) = pk;
        }
    }
}

__global__ __launch_bounds__(256) void cvt_bf16(
    const float* __restrict__ in, unsigned short* __restrict__ out, int n)
{
    const int i = (blockIdx.x * 256 + threadIdx.x) * 4;
    if (i >= n) return;
    f32x4 v = *reinterpret_cast<const f32x4*>(&in[i]);
    u16x4 pk;
    #pragma unroll
    for (int j = 0; j < 4; ++j) pk[j] = f2bf(v[j]);
    *reinterpret_cast<u16x4*>(&out[i]) = pk;
}

// ---------------------------------------------------------------------------
// Per-layer weight pack: fp32 -> bf16, Q parts scaled by 0.125 (exact).
//   [0,3DD) sa qkv  [3DD,6DD) ca qkv  [6DD,7DD) sa_wo  [7DD,8DD) ca_wo
//   [8DD,12DD) w1   [12DD,16DD) w2
// ---------------------------------------------------------------------------
__global__ __launch_bounds__(256) void pack_layer_w(
    const float* __restrict__ sa_wq, const float* __restrict__ sa_wk, const float* __restrict__ sa_wv,
    const float* __restrict__ ca_wq, const float* __restrict__ ca_wk, const float* __restrict__ ca_wv,
    const float* __restrict__ sa_wo, const float* __restrict__ ca_wo,
    const float* __restrict__ w1,   const float* __restrict__ w2,
    unsigned short* __restrict__ dst, int layer)
{
    const size_t DD = 1024u * 1024u;
    const size_t e  = ((size_t)blockIdx.x * 256 + threadIdx.x) * 4;
    const float* src;
    float scale = 1.f;
    if (e < 3 * DD) {
        const int part = (int)(e / DD);
        src = (part == 0 ? sa_wq : part == 1 ? sa_wk : sa_wv) + layer * DD + (e % DD);
        if (part == 0) scale = 0.125f;
    } else if (e < 6 * DD) {
        const size_t r = e - 3 * DD;
        const int part = (int)(r / DD);
        src = (part == 0 ? ca_wq : part == 1 ? ca_wk : ca_wv) + layer * DD + (r % DD);
        if (part == 0) scale = 0.125f;
    } else if (e < 7 * DD)  { src = sa_wo + layer * DD + (e - 6 * DD); }
    else if (e < 8 * DD)    { src = ca_wo + layer * DD + (e - 7 * DD); }
    else if (e < 12 * DD)   { src = w1 + (size_t)layer * 4 * DD + (e - 8 * DD); }
    else                    { src = w2 + (size_t)layer * 4 * DD + (e - 12 * DD); }
    f32x4 v = *reinterpret_cast<const f32x4*>(src);
    u16x4 pk;
    #pragma unroll
    for (int j = 0; j < 4; ++j) pk[j] = f2bf(v[j] * scale);
    *reinterpret_cast<u16x4*>(&dst[e]) = pk;
}

__global__ __launch_bounds__(256) void pack_bias(
    const float* __restrict__ sa_bq, const float* __restrict__ sa_bk, const float* __restrict__ sa_bv,
    const float* __restrict__ ca_bq, const float* __restrict__ ca_bk, const float* __restrict__ ca_bv,
    float* __restrict__ sab, float* __restrict__ cab)
{
    const int idx = blockIdx.x * 256 + threadIdx.x;
    const int half = idx / 12288;
    const int r    = idx % 12288;
    const int l    = r / 3072;
    const int pc   = r % 3072;
    const int part = pc >> 10;
    const int c    = pc & 1023;
    const float* src = half == 0 ? (part == 0 ? sa_bq : part == 1 ? sa_bk : sa_bv)
                                 : (part == 0 ? ca_bq : part == 1 ? ca_bk : ca_bv);
    const float v = src[l * 1024 + c] * (part == 0 ? 0.125f : 1.f);
    (half ? cab : sab)[l * 3072 + pc] = v;
}

// ---------------------------------------------------------------------------
extern "C" void kernel_launch(void* const* d_in, const int* in_sizes, int n_in,
                              void* d_out, int out_size, void* d_ws, size_t ws_size,
                              hipStream_t stream)
{
    (void)in_sizes; (void)n_in; (void)out_size; (void)ws_size;
    const int M  = 4096;
    const int Dm = 1024;
    const size_t DD = (size_t)Dm * Dm;

    const float* tgt   = (const float*)d_in[0];
    const float* mem   = (const float*)d_in[1];
    const float* sa_wq = (const float*)d_in[2];
    const float* sa_wk = (const float*)d_in[3];
    const float* sa_wv = (const float*)d_in[4];
    const float* sa_wo = (const float*)d_in[5];
    const float* sa_bq = (const float*)d_in[6];
    const float* sa_bk = (const float*)d_in[7];
    const float* sa_bv = (const float*)d_in[8];
    const float* sa_bo = (const float*)d_in[9];
    const float* ca_wq = (const float*)d_in[10];
    const float* ca_wk = (const float*)d_in[11];
    const float* ca_wv = (const float*)d_in[12];
    const float* ca_wo = (const float*)d_in[13];
    const float* ca_bq = (const float*)d_in[14];
    const float* ca_bk = (const float*)d_in[15];
    const float* ca_bv = (const float*)d_in[16];
    const float* ca_bo = (const float*)d_in[17];
    const float* w1    = (const float*)d_in[18];
    const float* b1    = (const float*)d_in[19];
    const float* w2    = (const float*)d_in[20];
    const float* b2    = (const float*)d_in[21];
    const float* ln1g  = (const float*)d_in[22];
    const float* ln1b  = (const float*)d_in[23];
    const float* ln2g  = (const float*)d_in[24];
    const float* ln2b  = (const float*)d_in[25];
    const float* ln3g  = (const float*)d_in[26];
    const float* ln3b  = (const float*)d_in[27];
    const float* lnfg  = (const float*)d_in[28];
    const float* lnfb  = (const float*)d_in[29];

    char* p = (char*)d_ws;
    float*          x_f    = (float*)p;          p += (size_t)M * Dm * 4;
    unsigned short* x_b    = (unsigned short*)p; p += (size_t)M * Dm * 2;
    unsigned short* mem_b  = (unsigned short*)p; p += (size_t)M * Dm * 2;
    unsigned short* qkv_b  = (unsigned short*)p; p += (size_t)M * 3072 * 2;
    unsigned short* caq_b  = (unsigned short*)p; p += (size_t)M * Dm * 2;
    unsigned short* cakv_b = (unsigned short*)p; p += (size_t)M * 2048 * 2;
    unsigned short* ao_b   = (unsigned short*)p; p += (size_t)M * Dm * 2;
    unsigned short* wpack  = (unsigned short*)p; p += 16 * DD * 2;
    float*          sab    = (float*)p;          p += 4 * 3072 * 4;
    float*          cab    = (float*)p;          p += 4 * 3072 * 4;
    unsigned short* h_b    = qkv_b;
    float*          z_f    = (float*)d_out;

    dim3 blk(256);
    auto gemm = [&](const unsigned short* A, const unsigned short* Bw, const float* bias,
                    const float* resid, unsigned short* ob, float* of, int N, int K, int mode) {
        dim3 grid(N / 128, M / 128);
        gemm_bt<<<grid, blk, 0, stream>>>(A, Bw, bias, resid, ob, of, M, N, K, mode);
    };

    cvt_bf16<<<4096, blk, 0, stream>>>(tgt, x_b, M * Dm);
    cvt_bf16<<<4096, blk, 0, stream>>>(mem, mem_b, M * Dm);
    pack_bias<<<96, blk, 0, stream>>>(sa_bq, sa_bk, sa_bv, ca_bq, ca_bk, ca_bv, sab, cab);

    const float* res = tgt;
    for (int i = 0; i < 4; ++i) {
        pack_layer_w<<<16384, blk, 0, stream>>>(sa_wq, sa_wk, sa_wv, ca_wq, ca_wk, ca_wv,
                                                sa_wo, ca_wo, w1, w2, wpack, i);
        // --- self-attention (fused QKV, N=3072) ---
        gemm(x_b, wpack, sab + i * 3072, nullptr, qkv_b, nullptr, 3072, 1024, 0);
        attn_fused<<<256, blk, 0, stream>>>(qkv_b, 3072, qkv_b + 1024, 3072, qkv_b + 2048, 3072, ao_b, 1);
        gemm(ao_b, wpack + 6 * DD, sa_bo + i * Dm, res, nullptr, z_f, 1024, 1024, 2);
        ln_kernel<<<1024, blk, 0, stream>>>(z_f, ln1g + i * Dm, ln1b + i * Dm, x_f, x_b);
        res = x_f;
        // --- cross-attention (Q from x; fused KV from memory, N=2048) ---
        gemm(x_b,   wpack + 3 * DD, cab + i * 3072,        nullptr, caq_b,  nullptr, 1024, 1024, 0);
        gemm(mem_b, wpack + 4 * DD, cab + i * 3072 + 1024, nullptr, cakv_b, nullptr, 2048, 1024, 0);
        attn_fused<<<256, blk, 0, stream>>>(caq_b, 1024, cakv_b, 2048, cakv_b + 1024, 2048, ao_b, 0);
        gemm(ao_b, wpack + 7 * DD, ca_bo + i * Dm, x_f, nullptr, z_f, 1024, 1024, 2);
        ln_kernel<<<1024, blk, 0, stream>>>(z_f, ln2g + i * Dm, ln2b + i * Dm, x_f, x_b);
        // --- FFN ---
        gemm(x_b, wpack + 8 * DD,  b1 + i * 4096, nullptr, h_b, nullptr, 4096, 1024, 1);
        gemm(h_b, wpack + 12 * DD, b2 + i * Dm,   x_f, nullptr, z_f, 1024, 4096, 2);
        ln_kernel<<<1024, blk, 0, stream>>>(z_f, ln3g + i * Dm, ln3b + i * Dm, x_f, x_b);
    }
    ln_kernel<<<1024, blk, 0, stream>>>(x_f, lnfg, lnfb, (float*)d_out, nullptr);
}

// Round 4
// 1578.292 us; speedup vs baseline: 1.7991x; 1.0091x over previous
//
#include <hip/hip_runtime.h>

// ---------------------------------------------------------------------------
// 4-layer transformer decoder, bf16 MFMA implementation (round 4).
// Big GEMMs: 256x256 tile, 8 waves, BK=32, 4-buffer LDS, depth-3 prefetch
// with counted vmcnt (never 0 in steady state), raw s_barrier. N=1024
// projections stay on the 128x128 2-phase kernel. FFN2 = split-K2 with
// reduce fused into LN3.
// ---------------------------------------------------------------------------

typedef __attribute__((ext_vector_type(4))) float f32x4;
typedef __attribute__((ext_vector_type(8))) short bf16x8;
typedef __attribute__((ext_vector_type(4))) unsigned short u16x4;
typedef __attribute__((ext_vector_type(4))) unsigned int   u32x4;

__device__ __forceinline__ unsigned short f2bf(float f) {
    unsigned int u = __builtin_bit_cast(unsigned int, f);
    u += 0x7fffu + ((u >> 16) & 1u);   // RNE
    return (unsigned short)(u >> 16);
}

__device__ __forceinline__ void gll16(const unsigned short* g, unsigned short* l) {
    auto* gp = reinterpret_cast<const __attribute__((address_space(1))) unsigned int*>(
        reinterpret_cast<uintptr_t>(g));
    auto* lp = reinterpret_cast<__attribute__((address_space(3))) unsigned int*>(
        reinterpret_cast<uintptr_t>(l));
    __builtin_amdgcn_global_load_lds(gp, lp, 16, 0, 0);
}

// ---------------------------------------------------------------------------
// gemm256: out = epilogue( A(bf16)[M][lda] @ Bw(bf16)[N][lda]^T ), K-extent
// klen starting at col blockIdx.z*klen. 256x256 tile, 8 waves (2Mx4N),
// per-wave 128x64 via acc[8][4]. Depth-3 pipeline, counted vmcnt.
// mode 0: bf16(acc+bias)  mode 1: bf16(relu(acc+bias))  mode 3: raw f32
// partial -> outf0 (z=0) / outf1 (z=1).
// ---------------------------------------------------------------------------
__global__ __launch_bounds__(512, 2) void gemm256(
    const unsigned short* __restrict__ A,
    const unsigned short* __restrict__ Bw,
    const float* __restrict__ bias,
    unsigned short* __restrict__ outb,
    float* __restrict__ outf0,
    float* __restrict__ outf1,
    int N, int lda, int klen, int mode)
{
    __shared__ unsigned short Al[4][256 * 32];
    __shared__ unsigned short Bl[4][256 * 32];
    const int tid  = threadIdx.x;
    const int lane = tid & 63;
    const int wid  = tid >> 6;          // 0..7
    const int wr   = wid >> 2;          // 0..1 -> rows wr*128
    const int wc   = wid & 3;           // 0..3 -> cols wc*64
    const int l15  = lane & 15;
    const int l4   = lane >> 4;
    const int m0   = blockIdx.y * 256;
    const int n0   = blockIdx.x * 256;
    const int kz   = blockIdx.z * klen;

    // staging: wave wid covers rows wid*16..wid*16+15 (+128 for j=1);
    // lane slot (lane&3) holds global k-chunk (lane&3)^s(row), s(r)=(r>>1)&3
    // (j-independent since 128>>1 ≡ 0 mod 4).
    const int srow   = wid * 16 + (lane >> 2);
    const int schunk = (lane & 3) ^ ((srow >> 1) & 3);
    const unsigned short* a_src = A  + (size_t)(m0 + srow) * lda + kz + schunk * 8;
    const unsigned short* b_src = Bw + (size_t)(n0 + srow) * lda + kz + schunk * 8;
    const size_t jstep = (size_t)128 * lda;
    const int lofs = (wid * 16) * 32;

    // fragment read offsets: row r (in tile), chunk l4 at slot l4^((r>>1)&3)
    int aofs[8], bofs[4];
    #pragma unroll
    for (int mi = 0; mi < 8; ++mi) {
        const int r = wr * 128 + mi * 16 + l15;
        aofs[mi] = r * 32 + ((l4 ^ ((r >> 1) & 3)) * 8);
    }
    #pragma unroll
    for (int ni = 0; ni < 4; ++ni) {
        const int r = wc * 64 + ni * 16 + l15;
        bofs[ni] = r * 32 + ((l4 ^ ((r >> 1) & 3)) * 8);
    }

    f32x4 acc[8][4];
    #pragma unroll
    for (int mi = 0; mi < 8; ++mi)
        #pragma unroll
        for (int ni = 0; ni < 4; ++ni)
            acc[mi][ni] = (f32x4){0.f, 0.f, 0.f, 0.f};

    auto STAGE = [&](int tt) {                       // 4 gll / thread
        const int buf = tt & 3;
        const unsigned short* ak = a_src + tt * 32;
        const unsigned short* bk = b_src + tt * 32;
        #pragma unroll
        for (int j = 0; j < 2; ++j) {
            gll16(ak + j * jstep, &Al[buf][lofs + j * 128 * 32]);
            gll16(bk + j * jstep, &Bl[buf][lofs + j * 128 * 32]);
        }
    };

    const int NT = klen >> 5;
    STAGE(0); STAGE(1); STAGE(2);
    for (int t = 0; t < NT; ++t) {
        if (t + 3 < NT) STAGE(t + 3);                // into buf[(t+3)&3] = buf freed at t-1
        const int rem = NT - 1 - t;
        __builtin_amdgcn_sched_barrier(0);
        if (rem >= 3)      asm volatile("s_waitcnt vmcnt(12)" ::: "memory");
        else if (rem == 2) asm volatile("s_waitcnt vmcnt(8)"  ::: "memory");
        else if (rem == 1) asm volatile("s_waitcnt vmcnt(4)"  ::: "memory");
        else               asm volatile("s_waitcnt vmcnt(0)"  ::: "memory");
        __builtin_amdgcn_sched_barrier(0);
        __builtin_amdgcn_s_barrier();                // all waves: buf[t&3] ready
        __builtin_amdgcn_sched_barrier(0);

        const unsigned short* ab = Al[t & 3];
        const unsigned short* bb = Bl[t & 3];
        bf16x8 af[8], bfv[4];
        #pragma unroll
        for (int mi = 0; mi < 8; ++mi) af[mi] = *reinterpret_cast<const bf16x8*>(&ab[aofs[mi]]);
        #pragma unroll
        for (int ni = 0; ni < 4; ++ni) bfv[ni] = *reinterpret_cast<const bf16x8*>(&bb[bofs[ni]]);
        #pragma unroll
        for (int mi = 0; mi < 8; ++mi)
            #pragma unroll
            for (int ni = 0; ni < 4; ++ni)
                acc[mi][ni] = __builtin_amdgcn_mfma_f32_16x16x32_bf16(af[mi], bfv[ni], acc[mi][ni], 0, 0, 0);

        __builtin_amdgcn_s_barrier();                // all reads of buf[t&3] drained
        __builtin_amdgcn_sched_barrier(0);
    }

    // epilogue: C/D layout col = lane&15, row = (lane>>4)*4 + r
    float* po = blockIdx.z == 0 ? outf0 : outf1;
    #pragma unroll
    for (int mi = 0; mi < 8; ++mi) {
        #pragma unroll
        for (int ni = 0; ni < 4; ++ni) {
            const int col = n0 + wc * 64 + ni * 16 + l15;
            const float bs = (mode == 3) ? 0.f : bias[col];
            #pragma unroll
            for (int r = 0; r < 4; ++r) {
                const int row = m0 + wr * 128 + mi * 16 + l4 * 4 + r;
                const float val = acc[mi][ni][r] + bs;
                if (mode == 0)      outb[(size_t)row * N + col] = f2bf(val);
                else if (mode == 1) outb[(size_t)row * N + col] = f2bf(fmaxf(val, 0.f));
                else                po[(size_t)row * N + col] = val;
            }
        }
    }
}

// ---------------------------------------------------------------------------
// gemm_bt (128x128, 2-phase dbuf): for N=1024 projections.
// mode 0: bf16(acc+bias)   mode 2: f32 acc+bias+resid
// ---------------------------------------------------------------------------
__global__ __launch_bounds__(256) void gemm_bt(
    const unsigned short* __restrict__ A,
    const unsigned short* __restrict__ Bw,
    const float* __restrict__ bias,
    const float* __restrict__ resid,
    unsigned short* __restrict__ outb,
    float* __restrict__ outf,
    int M, int N, int K, int mode)
{
    __shared__ unsigned short Al[2][128 * 32];
    __shared__ unsigned short Bl[2][128 * 32];
    const int tid  = threadIdx.x;
    const int lane = tid & 63;
    const int w    = tid >> 6;
    const int wr   = (w >> 1) * 64;
    const int wc   = (w & 1) * 64;
    const int l15  = lane & 15;
    const int l4   = lane >> 4;

    const int gx = gridDim.x, gy = gridDim.y;
    const int orig = blockIdx.y * gx + blockIdx.x;
    const int xcd  = orig & 7;
    const int lin  = orig >> 3;
    const int rpb  = gy >> 3;
    const int m0   = (xcd * rpb + (lin % rpb)) * 128;
    const int n0   = (lin / rpb) * 128;

    const int srow0 = w * 16 + (lane >> 2);
    const int scol  = ((lane & 3) ^ ((srow0 >> 1) & 3)) * 8;
    const unsigned short* ag = A  + (size_t)(m0 + srow0) * K + scol;
    const unsigned short* bg = Bw + (size_t)(n0 + srow0) * K + scol;
    const size_t jstep = (size_t)64 * K;
    const int lbase = (w * 16) * 32;

    int aoff[4], boff[4];
    #pragma unroll
    for (int i = 0; i < 4; ++i) {
        const int ra = wr + i * 16 + l15;
        const int rb = wc + i * 16 + l15;
        aoff[i] = ra * 32 + ((l4 ^ ((ra >> 1) & 3)) * 8);
        boff[i] = rb * 32 + ((l4 ^ ((rb >> 1) & 3)) * 8);
    }

    f32x4 acc[4][4];
    #pragma unroll
    for (int mi = 0; mi < 4; ++mi)
        #pragma unroll
        for (int ni = 0; ni < 4; ++ni)
            acc[mi][ni] = (f32x4){0.f, 0.f, 0.f, 0.f};

    #pragma unroll
    for (int j = 0; j < 2; ++j) {
        gll16(ag + j * jstep, &Al[0][lbase + j * 64 * 32]);
        gll16(bg + j * jstep, &Bl[0][lbase + j * 64 * 32]);
    }
    __syncthreads();

    const int nt = K >> 5;
    int cur = 0;
    for (int t = 0; t < nt; ++t) {
        if (t + 1 < nt) {
            ag += 32; bg += 32;
            #pragma unroll
            for (int j = 0; j < 2; ++j) {
                gll16(ag + j * jstep, &Al[cur ^ 1][lbase + j * 64 * 32]);
                gll16(bg + j * jstep, &Bl[cur ^ 1][lbase + j * 64 * 32]);
            }
        }
        const unsigned short* ac = &Al[cur][0];
        const unsigned short* bc = &Bl[cur][0];
        bf16x8 af[4], bf[4];
        #pragma unroll
        for (int i = 0; i < 4; ++i) af[i] = *reinterpret_cast<const bf16x8*>(&ac[aoff[i]]);
        #pragma unroll
        for (int i = 0; i < 4; ++i) bf[i] = *reinterpret_cast<const bf16x8*>(&bc[boff[i]]);
        #pragma unroll
        for (int mi = 0; mi < 4; ++mi)
            #pragma unroll
            for (int ni = 0; ni < 4; ++ni)
                acc[mi][ni] = __builtin_amdgcn_mfma_f32_16x16x32_bf16(af[mi], bf[ni], acc[mi][ni], 0, 0, 0);
        __syncthreads();
        cur ^= 1;
    }

    #pragma unroll
    for (int mi = 0; mi < 4; ++mi) {
        #pragma unroll
        for (int ni = 0; ni < 4; ++ni) {
            const int col = n0 + wc + ni * 16 + l15;
            const float bs = bias[col];
            #pragma unroll
            for (int r = 0; r < 4; ++r) {
                const int row = m0 + wr + mi * 16 + l4 * 4 + r;
                const float val = acc[mi][ni][r] + bs;
                if (mode == 0)      outb[(size_t)row * N + col] = f2bf(val);
                else                outf[(size_t)row * N + col] = val + resid[(size_t)row * N + col];
            }
        }
    }
}

// ---------------------------------------------------------------------------
// Fused attention: one workgroup per (n,h). T=S=256, hd=64.
// ---------------------------------------------------------------------------
__global__ __launch_bounds__(256) void attn_fused(
    const unsigned short* __restrict__ Q, int qs,
    const unsigned short* __restrict__ Kb, int ks_,
    const unsigned short* __restrict__ Vb, int vs,
    unsigned short* __restrict__ O,
    int causal)
{
    __shared__ unsigned short Kl[8][256][8];
    __shared__ unsigned short Vt[32][64][8];
    __shared__ unsigned short Pl[4][32][16][8];
    const int tid  = threadIdx.x;
    const int lane = tid & 63;
    const int w    = tid >> 6;
    const int n    = blockIdx.x >> 4;
    const int h    = blockIdx.x & 15;
    const int l15  = lane & 15;
    const int l4   = lane >> 4;
    const size_t hoff = (size_t)h * 64;

    #pragma unroll
    for (int i = 0; i < 8; ++i) {
        const int e = i * 256 + tid;
        const int s = e >> 3;
        const int c = e & 7;
        u32x4 kv = *reinterpret_cast<const u32x4*>(&Kb[((size_t)s * 16 + n) * ks_ + hoff + c * 8]);
        *reinterpret_cast<u32x4*>(&Kl[c][s][0]) = kv;
        u32x4 vv = *reinterpret_cast<const u32x4*>(&Vb[((size_t)s * 16 + n) * vs + hoff + c * 8]);
        const unsigned short* ve = reinterpret_cast<const unsigned short*>(&vv);
        #pragma unroll
        for (int j = 0; j < 8; ++j)
            Vt[s >> 3][c * 8 + j][s & 7] = ve[j];
    }
    __syncthreads();

    for (int ch = 0; ch < 4; ++ch) {
        const int t0 = w * 64 + ch * 16;
        bf16x8 qa[2];
        #pragma unroll
        for (int ks = 0; ks < 2; ++ks)
            qa[ks] = *reinterpret_cast<const bf16x8*>(
                &Q[((size_t)(t0 + l15) * 16 + n) * qs + hoff + ks * 32 + l4 * 8]);

        f32x4 sc[16];
        #pragma unroll
        for (int st = 0; st < 16; ++st) {
            f32x4 a = (f32x4){0.f, 0.f, 0.f, 0.f};
            #pragma unroll
            for (int ks = 0; ks < 2; ++ks) {
                bf16x8 kf = *reinterpret_cast<const bf16x8*>(&Kl[ks * 4 + l4][st * 16 + l15][0]);
                a = __builtin_amdgcn_mfma_f32_16x16x32_bf16(qa[ks], kf, a, 0, 0, 0);
            }
            sc[st] = a;
        }
        if (causal) {
            #pragma unroll
            for (int st = 0; st < 16; ++st) {
                const int sg = st * 16 + l15;
                #pragma unroll
                for (int r = 0; r < 4; ++r) {
                    const int tg = t0 + l4 * 4 + r;
                    if (sg > tg) sc[st][r] += -1e9f;
                }
            }
        }
        #pragma unroll
        for (int r = 0; r < 4; ++r) {
            float mx = -3.0e38f;
            #pragma unroll
            for (int st = 0; st < 16; ++st) mx = fmaxf(mx, sc[st][r]);
            #pragma unroll
            for (int dd = 1; dd < 16; dd <<= 1) mx = fmaxf(mx, __shfl_xor(mx, dd, 64));
            float sum = 0.f;
            #pragma unroll
            for (int st = 0; st < 16; ++st) {
                const float e = __expf(sc[st][r] - mx);
                sc[st][r] = e;
                sum += e;
            }
            #pragma unroll
            for (int dd = 1; dd < 16; dd <<= 1) sum += __shfl_xor(sum, dd, 64);
            const float inv = 1.f / sum;
            const int rl = l4 * 4 + r;
            #pragma unroll
            for (int st = 0; st < 16; ++st) {
                const int sg = st * 16 + l15;
                Pl[w][sg >> 3][rl][sg & 7] = f2bf(sc[st][r] * inv);
            }
        }
        f32x4 oacc[4];
        #pragma unroll
        for (int dt = 0; dt < 4; ++dt) oacc[dt] = (f32x4){0.f, 0.f, 0.f, 0.f};
        #pragma unroll
        for (int kt = 0; kt < 8; ++kt) {
            bf16x8 pa = *reinterpret_cast<const bf16x8*>(&Pl[w][kt * 4 + l4][l15][0]);
            #pragma unroll
            for (int dt = 0; dt < 4; ++dt) {
                bf16x8 vf = *reinterpret_cast<const bf16x8*>(&Vt[kt * 4 + l4][dt * 16 + l15][0]);
                oacc[dt] = __builtin_amdgcn_mfma_f32_16x16x32_bf16(pa, vf, oacc[dt], 0, 0, 0);
            }
        }
        #pragma unroll
        for (int dt = 0; dt < 4; ++dt)
            #pragma unroll
            for (int r = 0; r < 4; ++r)
                O[((size_t)(t0 + l4 * 4 + r) * 16 + n) * 1024 + hoff + dt * 16 + l15] = f2bf(oacc[dt][r]);
    }
}

// ---------------------------------------------------------------------------
// LayerNorm over D=1024, one wave per row (plain and fused-reduce variants)
// ---------------------------------------------------------------------------
__device__ __forceinline__ void ln_body(
    f32x4 (&v)[4], int row, int lane,
    const float* __restrict__ g, const float* __restrict__ b,
    float* __restrict__ xf, unsigned short* __restrict__ xb)
{
    float s = 0.f;
    #pragma unroll
    for (int i = 0; i < 4; ++i) s += v[i][0] + v[i][1] + v[i][2] + v[i][3];
    #pragma unroll
    for (int dd = 1; dd < 64; dd <<= 1) s += __shfl_xor(s, dd, 64);
    const float mu = s * (1.f / 1024.f);
    float q = 0.f;
    #pragma unroll
    for (int i = 0; i < 4; ++i)
        #pragma unroll
        for (int j = 0; j < 4; ++j) { const float d0 = v[i][j] - mu; q += d0 * d0; }
    #pragma unroll
    for (int dd = 1; dd < 64; dd <<= 1) q += __shfl_xor(q, dd, 64);
    const float rstd = rsqrtf(q * (1.f / 1024.f) + 1e-5f);
    #pragma unroll
    for (int i = 0; i < 4; ++i) {
        const int col = i * 256 + lane * 4;
        f32x4 gg = *reinterpret_cast<const f32x4*>(&g[col]);
        f32x4 bb = *reinterpret_cast<const f32x4*>(&b[col]);
        f32x4 y;
        #pragma unroll
        for (int j = 0; j < 4; ++j) y[j] = (v[i][j] - mu) * rstd * gg[j] + bb[j];
        if (xf) *reinterpret_cast<f32x4*>(&xf[(size_t)row * 1024 + col]) = y;
        if (xb) {
            u16x4 pk;
            #pragma unroll
            for (int j = 0; j < 4; ++j) pk[j] = f2bf(y[j]);
            *reinterpret_cast<u16x4*>(&xb[(size_t)row * 1024 + col]) = pk;
        }
    }
}

__global__ __launch_bounds__(256) void ln_kernel(
    const float* __restrict__ z, const float* __restrict__ g, const float* __restrict__ b,
    float* __restrict__ xf, unsigned short* __restrict__ xb)
{
    const int row  = blockIdx.x * 4 + (threadIdx.x >> 6);
    const int lane = threadIdx.x & 63;
    f32x4 v[4];
    #pragma unroll
    for (int i = 0; i < 4; ++i)
        v[i] = *reinterpret_cast<const f32x4*>(&z[(size_t)row * 1024 + i * 256 + lane * 4]);
    ln_body(v, row, lane, g, b, xf, xb);
}

// z = p0 + p1 + bias + resid, then LN. resid may alias xf (row-local).
__global__ __launch_bounds__(256) void ln_red2(
    const float* __restrict__ p0, const float* __restrict__ p1,
    const float* __restrict__ bias, const float* __restrict__ resid,
    const float* __restrict__ g, const float* __restrict__ b,
    float* __restrict__ xf, unsigned short* __restrict__ xb)
{
    const int row  = blockIdx.x * 4 + (threadIdx.x >> 6);
    const int lane = threadIdx.x & 63;
    f32x4 v[4];
    #pragma unroll
    for (int i = 0; i < 4; ++i) {
        const int col = i * 256 + lane * 4;
        const size_t o = (size_t)row * 1024 + col;
        f32x4 a0 = *reinterpret_cast<const f32x4*>(&p0[o]);
        f32x4 a1 = *reinterpret_cast<const f32x4*>(&p1[o]);
        f32x4 bs = *reinterpret_cast<const f32x4*>(&bias[col]);
        f32x4 rs = *reinterpret_cast<const f32x4*>(&resid[o]);
        v[i] = a0 + a1 + bs + rs;
    }
    ln_body(v, row, lane, g, b, xf, xb);
}

__global__ __launch_bounds__(256) void cvt_bf16(
    const float* __restrict__ in, unsigned short* __restrict__ out, int n)
{
    const int i = (blockIdx.x * 256 + threadIdx.x) * 4;
    if (i >= n) return;
    f32x4 v = *reinterpret_cast<const f32x4*>(&in[i]);
    u16x4 pk;
    #pragma unroll
    for (int j = 0; j < 4; ++j) pk[j] = f2bf(v[j]);
    *reinterpret_cast<u16x4*>(&out[i]) = pk;
}

// ---------------------------------------------------------------------------
// Per-layer weight pack (fp32->bf16, Q-scale folded):
//   [0,3DD) sa qkv  [3DD,6DD) ca qkv  [6DD,7DD) sa_wo  [7DD,8DD) ca_wo
//   [8DD,12DD) w1   [12DD,16DD) w2
// ---------------------------------------------------------------------------
__global__ __launch_bounds__(256) void pack_layer_w(
    const float* __restrict__ sa_wq, const float* __restrict__ sa_wk, const float* __restrict__ sa_wv,
    const float* __restrict__ ca_wq, const float* __restrict__ ca_wk, const float* __restrict__ ca_wv,
    const float* __restrict__ sa_wo, const float* __restrict__ ca_wo,
    const float* __restrict__ w1,   const float* __restrict__ w2,
    unsigned short* __restrict__ dst, int layer)
{
    const size_t DD = 1024u * 1024u;
    const size_t e  = ((size_t)blockIdx.x * 256 + threadIdx.x) * 4;
    const float* src;
    float scale = 1.f;
    if (e < 3 * DD) {
        const int part = (int)(e / DD);
        src = (part == 0 ? sa_wq : part == 1 ? sa_wk : sa_wv) + layer * DD + (e % DD);
        if (part == 0) scale = 0.125f;
    } else if (e < 6 * DD) {
        const size_t r = e - 3 * DD;
        const int part = (int)(r / DD);
        src = (part == 0 ? ca_wq : part == 1 ? ca_wk : ca_wv) + layer * DD + (r % DD);
        if (part == 0) scale = 0.125f;
    } else if (e < 7 * DD)  { src = sa_wo + layer * DD + (e - 6 * DD); }
    else if (e < 8 * DD)    { src = ca_wo + layer * DD + (e - 7 * DD); }
    else if (e < 12 * DD)   { src = w1 + (size_t)layer * 4 * DD + (e - 8 * DD); }
    else                    { src = w2 + (size_t)layer * 4 * DD + (e - 12 * DD); }
    f32x4 v = *reinterpret_cast<const f32x4*>(src);
    u16x4 pk;
    #pragma unroll
    for (int j = 0; j < 4; ++j) pk[j] = f2bf(v[j] * scale);
    *reinterpret_cast<u16x4*>(&dst[e]) = pk;
}

__global__ __launch_bounds__(256) void pack_bias(
    const float* __restrict__ sa_bq, const float* __restrict__ sa_bk, const float* __restrict__ sa_bv,
    const float* __restrict__ ca_bq, const float* __restrict__ ca_bk, const float* __restrict__ ca_bv,
    float* __restrict__ sab, float* __restrict__ cab)
{
    const int idx = blockIdx.x * 256 + threadIdx.x;
    const int half = idx / 12288;
    const int r    = idx % 12288;
    const int l    = r / 3072;
    const int pc   = r % 3072;
    const int part = pc >> 10;
    const int c    = pc & 1023;
    const float* src = half == 0 ? (part == 0 ? sa_bq : part == 1 ? sa_bk : sa_bv)
                                 : (part == 0 ? ca_bq : part == 1 ? ca_bk : ca_bv);
    const float v = src[l * 1024 + c] * (part == 0 ? 0.125f : 1.f);
    (half ? cab : sab)[l * 3072 + pc] = v;
}

// ---------------------------------------------------------------------------
extern "C" void kernel_launch(void* const* d_in, const int* in_sizes, int n_in,
                              void* d_out, int out_size, void* d_ws, size_t ws_size,
                              hipStream_t stream)
{
    (void)in_sizes; (void)n_in; (void)out_size; (void)ws_size;
    const int M  = 4096;
    const int Dm = 1024;
    const size_t DD = (size_t)Dm * Dm;

    const float* tgt   = (const float*)d_in[0];
    const float* mem   = (const float*)d_in[1];
    const float* sa_wq = (const float*)d_in[2];
    const float* sa_wk = (const float*)d_in[3];
    const float* sa_wv = (const float*)d_in[4];
    const float* sa_wo = (const float*)d_in[5];
    const float* sa_bq = (const float*)d_in[6];
    const float* sa_bk = (const float*)d_in[7];
    const float* sa_bv = (const float*)d_in[8];
    const float* sa_bo = (const float*)d_in[9];
    const float* ca_wq = (const float*)d_in[10];
    const float* ca_wk = (const float*)d_in[11];
    const float* ca_wv = (const float*)d_in[12];
    const float* ca_wo = (const float*)d_in[13];
    const float* ca_bq = (const float*)d_in[14];
    const float* ca_bk = (const float*)d_in[15];
    const float* ca_bv = (const float*)d_in[16];
    const float* ca_bo = (const float*)d_in[17];
    const float* w1    = (const float*)d_in[18];
    const float* b1    = (const float*)d_in[19];
    const float* w2    = (const float*)d_in[20];
    const float* b2    = (const float*)d_in[21];
    const float* ln1g  = (const float*)d_in[22];
    const float* ln1b  = (const float*)d_in[23];
    const float* ln2g  = (const float*)d_in[24];
    const float* ln2b  = (const float*)d_in[25];
    const float* ln3g  = (const float*)d_in[26];
    const float* ln3b  = (const float*)d_in[27];
    const float* lnfg  = (const float*)d_in[28];
    const float* lnfb  = (const float*)d_in[29];

    // workspace layout (~126 MB); FFN hidden h_b spans qkv_b+cakv_b (dead
    // then); FFN2 split-K partials: p0 after h_b end, p1 in dead wpack[0,12DD)
    char* p = (char*)d_ws;
    float*          x_f    = (float*)p;          p += (size_t)M * Dm * 4;       // 16.78 MB
    unsigned short* x_b    = (unsigned short*)p; p += (size_t)M * Dm * 2;
    unsigned short* mem_b  = (unsigned short*)p; p += (size_t)M * Dm * 2;
    unsigned short* qkv_b  = (unsigned short*)p; p += (size_t)M * 3072 * 2;     // 25.17 MB
    unsigned short* cakv_b = (unsigned short*)p; p += (size_t)M * 2048 * 2;     // 16.78 MB
    unsigned short* caq_b  = (unsigned short*)p; p += (size_t)M * Dm * 2;
    unsigned short* ao_b   = (unsigned short*)p; p += (size_t)M * Dm * 2;
    unsigned short* wpack  = (unsigned short*)p; p += 16 * DD * 2;              // 33.55 MB
    float*          sab    = (float*)p;          p += 4 * 3072 * 4;
    float*          cab    = (float*)p;          p += 4 * 3072 * 4;
    unsigned short* h_b    = qkv_b;                                             // [4096][4096] bf16
    float*          par0   = (float*)((char*)qkv_b + (size_t)M * 4096 * 2);     // 16.78 MB (dead cakv tail+caq+ao)
    float*          par1   = (float*)wpack;                                     // 16.78 MB (dead packed weights)
    float*          z_f    = (float*)d_out;

    dim3 blk(256), blk5(512);
    auto gemm128 = [&](const unsigned short* A, const unsigned short* Bw, const float* bias,
                       const float* resid, unsigned short* ob, float* of, int N, int K, int mode) {
        dim3 grid(N / 128, M / 128);
        gemm_bt<<<grid, blk, 0, stream>>>(A, Bw, bias, resid, ob, of, M, N, K, mode);
    };

    cvt_bf16<<<4096, blk, 0, stream>>>(tgt, x_b, M * Dm);
    cvt_bf16<<<4096, blk, 0, stream>>>(mem, mem_b, M * Dm);
    pack_bias<<<96, blk, 0, stream>>>(sa_bq, sa_bk, sa_bv, ca_bq, ca_bk, ca_bv, sab, cab);

    const float* res = tgt;
    for (int i = 0; i < 4; ++i) {
        pack_layer_w<<<16384, blk, 0, stream>>>(sa_wq, sa_wk, sa_wv, ca_wq, ca_wk, ca_wv,
                                                sa_wo, ca_wo, w1, w2, wpack, i);
        // --- self-attention (fused QKV, N=3072) ---
        gemm256<<<dim3(12, 16, 1), blk5, 0, stream>>>(x_b, wpack, sab + i * 3072,
            qkv_b, nullptr, nullptr, 3072, 1024, 1024, 0);
        attn_fused<<<256, blk, 0, stream>>>(qkv_b, 3072, qkv_b + 1024, 3072, qkv_b + 2048, 3072, ao_b, 1);
        gemm128(ao_b, wpack + 6 * DD, sa_bo + i * Dm, res, nullptr, z_f, 1024, 1024, 2);
        ln_kernel<<<1024, blk, 0, stream>>>(z_f, ln1g + i * Dm, ln1b + i * Dm, x_f, x_b);
        res = x_f;
        // --- cross-attention (Q from x; fused KV from memory, N=2048) ---
        gemm128(x_b, wpack + 3 * DD, cab + i * 3072, nullptr, caq_b, nullptr, 1024, 1024, 0);
        gemm256<<<dim3(8, 16, 1), blk5, 0, stream>>>(mem_b, wpack + 4 * DD, cab + i * 3072 + 1024,
            cakv_b, nullptr, nullptr, 2048, 1024, 1024, 0);
        attn_fused<<<256, blk, 0, stream>>>(caq_b, 1024, cakv_b, 2048, cakv_b + 1024, 2048, ao_b, 0);
        gemm128(ao_b, wpack + 7 * DD, ca_bo + i * Dm, x_f, nullptr, z_f, 1024, 1024, 2);
        ln_kernel<<<1024, blk, 0, stream>>>(z_f, ln2g + i * Dm, ln2b + i * Dm, x_f, x_b);
        // --- FFN ---
        gemm256<<<dim3(16, 16, 1), blk5, 0, stream>>>(x_b, wpack + 8 * DD, b1 + i * 4096,
            h_b, nullptr, nullptr, 4096, 1024, 1024, 1);
        gemm256<<<dim3(4, 16, 2), blk5, 0, stream>>>(h_b, wpack + 12 * DD, nullptr,
            nullptr, par0, par1, 1024, 4096, 2048, 3);
        ln_red2<<<1024, blk, 0, stream>>>(par0, par1, b2 + i * Dm, x_f,
            ln3g + i * Dm, ln3b + i * Dm, x_f, x_b);
    }
    ln_kernel<<<1024, blk, 0, stream>>>(x_f, lnfg, lnfb, (float*)d_out, nullptr);
}

// Round 5
// 1466.469 us; speedup vs baseline: 1.9363x; 1.0763x over previous
//
#include <hip/hip_runtime.h>

// ---------------------------------------------------------------------------
// 4-layer transformer decoder, bf16 MFMA implementation (round 5).
// Big GEMMs: 256x256 tile, 8 waves, BK=64, 2-buffer LDS, 8-phase schedule
// (4 phases/K-tile: quadrant MFMA + 1 half-tile stage + counted vmcnt(4),
// never drained in steady state), setprio around MFMA. N=1024 GEMMs:
// 64x128 tile 2-phase dbuf at 2 blocks/CU.
// ---------------------------------------------------------------------------

typedef __attribute__((ext_vector_type(4))) float f32x4;
typedef __attribute__((ext_vector_type(8))) short bf16x8;
typedef __attribute__((ext_vector_type(4))) unsigned short u16x4;
typedef __attribute__((ext_vector_type(4))) unsigned int   u32x4;

__device__ __forceinline__ unsigned short f2bf(float f) {
    unsigned int u = __builtin_bit_cast(unsigned int, f);
    u += 0x7fffu + ((u >> 16) & 1u);   // RNE
    return (unsigned short)(u >> 16);
}

__device__ __forceinline__ void gll16(const unsigned short* g, unsigned short* l) {
    auto* gp = reinterpret_cast<const __attribute__((address_space(1))) unsigned int*>(
        reinterpret_cast<uintptr_t>(g));
    auto* lp = reinterpret_cast<__attribute__((address_space(3))) unsigned int*>(
        reinterpret_cast<uintptr_t>(l));
    __builtin_amdgcn_global_load_lds(gp, lp, 16, 0, 0);
}

// ---------------------------------------------------------------------------
// gemm256: out = epilogue( A(bf16)[M][lda] @ Bw(bf16)[N][lda]^T ), K range
// [kz, kz+klen) with kz = blockIdx.z*klen. 8 waves (2M x 4N), per-wave
// 128x64 output. LDS [2 buf][256][64] per operand (128 KiB).
// mode 0: bf16(acc+bias)  1: bf16(relu(acc+bias))  3: raw f32 -> outf{0,1}
// ---------------------------------------------------------------------------
__global__ __launch_bounds__(512, 2) void gemm256(
    const unsigned short* __restrict__ A,
    const unsigned short* __restrict__ Bw,
    const float* __restrict__ bias,
    unsigned short* __restrict__ outb,
    float* __restrict__ outf0,
    float* __restrict__ outf1,
    int N, int lda, int klen, int mode)
{
    __shared__ unsigned short Al[2][256 * 64];
    __shared__ unsigned short Bl[2][256 * 64];
    const int tid  = threadIdx.x;
    const int lane = tid & 63;
    const int wid  = tid >> 6;              // 0..7
    const int wrb  = (wid >> 2) * 128;      // wave row base in tile
    const int wcb  = (wid & 3) * 64;        // wave col base in tile
    const int l15  = lane & 15;
    const int l4   = lane >> 4;
    const int m0   = blockIdx.y * 256;
    const int n0   = blockIdx.x * 256;
    const int kz   = blockIdx.z * klen;

    // ds_read per-lane core: frag at tile-row base R reads elem offset
    // R*64 + xo[kk], xo[kk] = l15*64 + ((kk*4+l4)^(l15&7))*8  (slot-XOR swz)
    int xo[2];
    #pragma unroll
    for (int kk = 0; kk < 2; ++kk)
        xo[kk] = l15 * 64 + (((kk * 4 + l4) ^ (l15 & 7)) * 8);

    // staging per-lane core: lane covers row (lane>>3) of its 8-row block,
    // slot lane&7; global source chunk pre-swizzled: (lane&7)^(pr&7), and
    // pr&7 == lane>>3 for 8-aligned blocks.
    const size_t lsrc = (size_t)(lane >> 3) * lda + (((lane & 7) ^ (lane >> 3)) * 8);
    const unsigned short* Ag = A  + (size_t)m0 * lda + kz + lsrc;
    const unsigned short* Bg = Bw + (size_t)n0 * lda + kz + lsrc;

    f32x4 acc[8][4];
    #pragma unroll
    for (int mi = 0; mi < 8; ++mi)
        #pragma unroll
        for (int ni = 0; ni < 4; ++ni)
            acc[mi][ni] = (f32x4){0.f, 0.f, 0.f, 0.f};

    // stage unit: 0=A_lo(rows 0-63,128-191) 1=B_lo 2=B_hi 3=A_hi  (16 KB, 2 gll)
    auto stage = [&](int tt, int unit) {
        const int buf = tt & 1;
        #pragma unroll
        for (int j = 0; j < 2; ++j) {
            const int u0 = wid * 16 + j * 8;       // 8-row block index base
            int pr0;
            unsigned short* lb;
            const unsigned short* gs;
            if (unit == 0)      { pr0 = (u0 < 64) ? u0 : u0 + 64;         lb = Al[buf]; gs = Ag; }
            else if (unit == 3) { pr0 = (u0 < 64) ? u0 + 64 : u0 + 128;   lb = Al[buf]; gs = Ag; }
            else if (unit == 1) { pr0 = (u0 >> 5) * 64 + (u0 & 31);       lb = Bl[buf]; gs = Bg; }
            else                { pr0 = (u0 >> 5) * 64 + 32 + (u0 & 31);  lb = Bl[buf]; gs = Bg; }
            gll16(gs + (size_t)pr0 * lda + tt * 64, lb + pr0 * 64);
        }
    };

    const int NT = klen >> 6;
    // prologue: tile 0 fully staged; wait A_lo+B_lo (oldest 4 of 8)
    stage(0, 0); stage(0, 1); stage(0, 2); stage(0, 3);
    __builtin_amdgcn_sched_barrier(0);
    asm volatile("s_waitcnt vmcnt(4)" ::: "memory");
    __builtin_amdgcn_sched_barrier(0);
    __builtin_amdgcn_s_barrier();

    bf16x8 af[4][2], bfr[2][2];
    for (int t = 0; t < NT; ++t) {
        const unsigned short* Ab = Al[t & 1];
        const unsigned short* Bb = Bl[t & 1];
        const bool pf = (t + 1 < NT);

        // ---------------- P1: Q(lo,lo) — reads A_lo + B_lo
        #pragma unroll
        for (int i = 0; i < 4; ++i)
            #pragma unroll
            for (int kk = 0; kk < 2; ++kk)
                af[i][kk] = *reinterpret_cast<const bf16x8*>(&Ab[(wrb + i * 16) * 64 + xo[kk]]);
        #pragma unroll
        for (int n = 0; n < 2; ++n)
            #pragma unroll
            for (int kk = 0; kk < 2; ++kk)
                bfr[n][kk] = *reinterpret_cast<const bf16x8*>(&Bb[(wcb + n * 16) * 64 + xo[kk]]);
        if (pf) stage(t + 1, 0);
        __builtin_amdgcn_sched_barrier(0);
        asm volatile("s_waitcnt lgkmcnt(0)" ::: "memory");
        __builtin_amdgcn_sched_barrier(0);
        __builtin_amdgcn_s_setprio(1);
        #pragma unroll
        for (int kk = 0; kk < 2; ++kk)
            #pragma unroll
            for (int i = 0; i < 4; ++i)
                #pragma unroll
                for (int n = 0; n < 2; ++n)
                    acc[i][n] = __builtin_amdgcn_mfma_f32_16x16x32_bf16(af[i][kk], bfr[n][kk], acc[i][n], 0, 0, 0);
        __builtin_amdgcn_s_setprio(0);
        __builtin_amdgcn_sched_barrier(0);
        if (pf) asm volatile("s_waitcnt vmcnt(4)" ::: "memory");   // B_hi(t) landed
        else    asm volatile("s_waitcnt vmcnt(2)" ::: "memory");
        __builtin_amdgcn_sched_barrier(0);
        __builtin_amdgcn_s_barrier();

        // ---------------- P2: Q(lo,hi) — reads B_hi (A_lo regs live)
        #pragma unroll
        for (int n = 0; n < 2; ++n)
            #pragma unroll
            for (int kk = 0; kk < 2; ++kk)
                bfr[n][kk] = *reinterpret_cast<const bf16x8*>(&Bb[(wcb + 32 + n * 16) * 64 + xo[kk]]);
        if (pf) stage(t + 1, 1);
        __builtin_amdgcn_sched_barrier(0);
        asm volatile("s_waitcnt lgkmcnt(0)" ::: "memory");
        __builtin_amdgcn_sched_barrier(0);
        __builtin_amdgcn_s_setprio(1);
        #pragma unroll
        for (int kk = 0; kk < 2; ++kk)
            #pragma unroll
            for (int i = 0; i < 4; ++i)
                #pragma unroll
                for (int n = 0; n < 2; ++n)
                    acc[i][2 + n] = __builtin_amdgcn_mfma_f32_16x16x32_bf16(af[i][kk], bfr[n][kk], acc[i][2 + n], 0, 0, 0);
        __builtin_amdgcn_s_setprio(0);
        __builtin_amdgcn_sched_barrier(0);
        if (pf) asm volatile("s_waitcnt vmcnt(4)" ::: "memory");   // A_hi(t) landed
        else    asm volatile("s_waitcnt vmcnt(0)" ::: "memory");
        __builtin_amdgcn_sched_barrier(0);
        __builtin_amdgcn_s_barrier();

        // ---------------- P3: Q(hi,hi) — reads A_hi (B_hi regs live)
        #pragma unroll
        for (int i = 0; i < 4; ++i)
            #pragma unroll
            for (int kk = 0; kk < 2; ++kk)
                af[i][kk] = *reinterpret_cast<const bf16x8*>(&Ab[(wrb + 64 + i * 16) * 64 + xo[kk]]);
        if (pf) stage(t + 1, 2);
        __builtin_amdgcn_sched_barrier(0);
        asm volatile("s_waitcnt lgkmcnt(0)" ::: "memory");
        __builtin_amdgcn_sched_barrier(0);
        __builtin_amdgcn_s_setprio(1);
        #pragma unroll
        for (int kk = 0; kk < 2; ++kk)
            #pragma unroll
            for (int i = 0; i < 4; ++i)
                #pragma unroll
                for (int n = 0; n < 2; ++n)
                    acc[4 + i][2 + n] = __builtin_amdgcn_mfma_f32_16x16x32_bf16(af[i][kk], bfr[n][kk], acc[4 + i][2 + n], 0, 0, 0);
        __builtin_amdgcn_s_setprio(0);
        __builtin_amdgcn_sched_barrier(0);
        __builtin_amdgcn_s_barrier();                              // no vmcnt here

        // ---------------- P4: Q(hi,lo) — re-reads B_lo (A_hi regs live)
        #pragma unroll
        for (int n = 0; n < 2; ++n)
            #pragma unroll
            for (int kk = 0; kk < 2; ++kk)
                bfr[n][kk] = *reinterpret_cast<const bf16x8*>(&Bb[(wcb + n * 16) * 64 + xo[kk]]);
        if (pf) stage(t + 1, 3);
        __builtin_amdgcn_sched_barrier(0);
        asm volatile("s_waitcnt lgkmcnt(0)" ::: "memory");
        __builtin_amdgcn_sched_barrier(0);
        __builtin_amdgcn_s_setprio(1);
        #pragma unroll
        for (int kk = 0; kk < 2; ++kk)
            #pragma unroll
            for (int i = 0; i < 4; ++i)
                #pragma unroll
                for (int n = 0; n < 2; ++n)
                    acc[4 + i][n] = __builtin_amdgcn_mfma_f32_16x16x32_bf16(af[i][kk], bfr[n][kk], acc[4 + i][n], 0, 0, 0);
        __builtin_amdgcn_s_setprio(0);
        __builtin_amdgcn_sched_barrier(0);
        if (pf) asm volatile("s_waitcnt vmcnt(4)" ::: "memory");   // A_lo+B_lo(t+1) landed
        __builtin_amdgcn_sched_barrier(0);
        __builtin_amdgcn_s_barrier();
    }

    // epilogue: C/D layout col = lane&15, row = (lane>>4)*4 + r
    float* po = (blockIdx.z == 0) ? outf0 : outf1;
    #pragma unroll
    for (int h = 0; h < 2; ++h) {
        #pragma unroll
        for (int i = 0; i < 4; ++i) {
            #pragma unroll
            for (int ni = 0; ni < 4; ++ni) {
                const int col = n0 + wcb + ni * 16 + l15;
                const float bs = (mode == 3) ? 0.f : bias[col];
                #pragma unroll
                for (int r = 0; r < 4; ++r) {
                    const int row = m0 + wrb + h * 64 + i * 16 + l4 * 4 + r;
                    const float val = acc[h * 4 + i][ni][r] + bs;
                    if (mode == 0)      outb[(size_t)row * N + col] = f2bf(val);
                    else if (mode == 1) outb[(size_t)row * N + col] = f2bf(fmaxf(val, 0.f));
                    else                po[(size_t)row * N + col] = val;
                }
            }
        }
    }
}

// ---------------------------------------------------------------------------
// gemm_bt64: 64x128 tile, BK=32, 2-phase dbuf, for N=1024 GEMMs (grid 512 ->
// 2 blocks/CU). mode 0: bf16(acc+bias)   mode 2: f32 acc+bias+resid
// ---------------------------------------------------------------------------
__global__ __launch_bounds__(256) void gemm_bt64(
    const unsigned short* __restrict__ A,
    const unsigned short* __restrict__ Bw,
    const float* __restrict__ bias,
    const float* __restrict__ resid,
    unsigned short* __restrict__ outb,
    float* __restrict__ outf,
    int M, int N, int K, int mode)
{
    __shared__ unsigned short Al[2][64 * 32];
    __shared__ unsigned short Bl[2][128 * 32];
    const int tid  = threadIdx.x;
    const int lane = tid & 63;
    const int w    = tid >> 6;
    const int wr   = (w >> 1) * 32;
    const int wc   = (w & 1) * 64;
    const int l15  = lane & 15;
    const int l4   = lane >> 4;

    // XCD band swizzle (gy=64 -> 8 row-blocks per XCD, column-major in band)
    const int gx = gridDim.x;
    const int orig = blockIdx.y * gx + blockIdx.x;
    const int xcd  = orig & 7;
    const int lin  = orig >> 3;
    const int m0   = (xcd * 8 + (lin & 7)) * 64;
    const int n0   = (lin >> 3) * 128;

    const int srow = w * 16 + (lane >> 2);
    const int scol = ((lane & 3) ^ ((srow >> 1) & 3)) * 8;
    const unsigned short* ag = A  + (size_t)(m0 + srow) * K + scol;
    const unsigned short* bg = Bw + (size_t)(n0 + srow) * K + scol;
    const size_t jstep = (size_t)64 * K;
    const int lbase = (w * 16) * 32;

    int aoff[2], boff[4];
    #pragma unroll
    for (int i = 0; i < 2; ++i) {
        const int ra = wr + i * 16 + l15;
        aoff[i] = ra * 32 + ((l4 ^ ((ra >> 1) & 3)) * 8);
    }
    #pragma unroll
    for (int i = 0; i < 4; ++i) {
        const int rb = wc + i * 16 + l15;
        boff[i] = rb * 32 + ((l4 ^ ((rb >> 1) & 3)) * 8);
    }

    f32x4 acc[2][4];
    #pragma unroll
    for (int mi = 0; mi < 2; ++mi)
        #pragma unroll
        for (int ni = 0; ni < 4; ++ni)
            acc[mi][ni] = (f32x4){0.f, 0.f, 0.f, 0.f};

    gll16(ag, &Al[0][lbase]);
    #pragma unroll
    for (int j = 0; j < 2; ++j) gll16(bg + j * jstep, &Bl[0][lbase + j * 64 * 32]);
    __syncthreads();

    const int nt = K >> 5;
    int cur = 0;
    for (int t = 0; t < nt; ++t) {
        if (t + 1 < nt) {
            ag += 32; bg += 32;
            gll16(ag, &Al[cur ^ 1][lbase]);
            #pragma unroll
            for (int j = 0; j < 2; ++j) gll16(bg + j * jstep, &Bl[cur ^ 1][lbase + j * 64 * 32]);
        }
        const unsigned short* ac = &Al[cur][0];
        const unsigned short* bc = &Bl[cur][0];
        bf16x8 af[2], bf[4];
        #pragma unroll
        for (int i = 0; i < 2; ++i) af[i] = *reinterpret_cast<const bf16x8*>(&ac[aoff[i]]);
        #pragma unroll
        for (int i = 0; i < 4; ++i) bf[i] = *reinterpret_cast<const bf16x8*>(&bc[boff[i]]);
        #pragma unroll
        for (int mi = 0; mi < 2; ++mi)
            #pragma unroll
            for (int ni = 0; ni < 4; ++ni)
                acc[mi][ni] = __builtin_amdgcn_mfma_f32_16x16x32_bf16(af[mi], bf[ni], acc[mi][ni], 0, 0, 0);
        __syncthreads();
        cur ^= 1;
    }

    #pragma unroll
    for (int mi = 0; mi < 2; ++mi) {
        #pragma unroll
        for (int ni = 0; ni < 4; ++ni) {
            const int col = n0 + wc + ni * 16 + l15;
            const float bs = bias[col];
            #pragma unroll
            for (int r = 0; r < 4; ++r) {
                const int row = m0 + wr + mi * 16 + l4 * 4 + r;
                const float val = acc[mi][ni][r] + bs;
                if (mode == 0) outb[(size_t)row * N + col] = f2bf(val);
                else           outf[(size_t)row * N + col] = val + resid[(size_t)row * N + col];
            }
        }
    }
}

// ---------------------------------------------------------------------------
// Fused attention: one workgroup per (n,h). T=S=256, hd=64.
// ---------------------------------------------------------------------------
__global__ __launch_bounds__(256) void attn_fused(
    const unsigned short* __restrict__ Q, int qs,
    const unsigned short* __restrict__ Kb, int ks_,
    const unsigned short* __restrict__ Vb, int vs,
    unsigned short* __restrict__ O,
    int causal)
{
    __shared__ unsigned short Kl[8][256][8];
    __shared__ unsigned short Vt[32][64][8];
    __shared__ unsigned short Pl[4][32][16][8];
    const int tid  = threadIdx.x;
    const int lane = tid & 63;
    const int w    = tid >> 6;
    const int n    = blockIdx.x >> 4;
    const int h    = blockIdx.x & 15;
    const int l15  = lane & 15;
    const int l4   = lane >> 4;
    const size_t hoff = (size_t)h * 64;

    #pragma unroll
    for (int i = 0; i < 8; ++i) {
        const int e = i * 256 + tid;
        const int s = e >> 3;
        const int c = e & 7;
        u32x4 kv = *reinterpret_cast<const u32x4*>(&Kb[((size_t)s * 16 + n) * ks_ + hoff + c * 8]);
        *reinterpret_cast<u32x4*>(&Kl[c][s][0]) = kv;
        u32x4 vv = *reinterpret_cast<const u32x4*>(&Vb[((size_t)s * 16 + n) * vs + hoff + c * 8]);
        const unsigned short* ve = reinterpret_cast<const unsigned short*>(&vv);
        #pragma unroll
        for (int j = 0; j < 8; ++j)
            Vt[s >> 3][c * 8 + j][s & 7] = ve[j];
    }
    __syncthreads();

    for (int ch = 0; ch < 4; ++ch) {
        const int t0 = w * 64 + ch * 16;
        bf16x8 qa[2];
        #pragma unroll
        for (int ks = 0; ks < 2; ++ks)
            qa[ks] = *reinterpret_cast<const bf16x8*>(
                &Q[((size_t)(t0 + l15) * 16 + n) * qs + hoff + ks * 32 + l4 * 8]);

        f32x4 sc[16];
        #pragma unroll
        for (int st = 0; st < 16; ++st) {
            f32x4 a = (f32x4){0.f, 0.f, 0.f, 0.f};
            #pragma unroll
            for (int ks = 0; ks < 2; ++ks) {
                bf16x8 kf = *reinterpret_cast<const bf16x8*>(&Kl[ks * 4 + l4][st * 16 + l15][0]);
                a = __builtin_amdgcn_mfma_f32_16x16x32_bf16(qa[ks], kf, a, 0, 0, 0);
            }
            sc[st] = a;
        }
        if (causal) {
            #pragma unroll
            for (int st = 0; st < 16; ++st) {
                const int sg = st * 16 + l15;
                #pragma unroll
                for (int r = 0; r < 4; ++r) {
                    const int tg = t0 + l4 * 4 + r;
                    if (sg > tg) sc[st][r] += -1e9f;
                }
            }
        }
        #pragma unroll
        for (int r = 0; r < 4; ++r) {
            float mx = -3.0e38f;
            #pragma unroll
            for (int st = 0; st < 16; ++st) mx = fmaxf(mx, sc[st][r]);
            #pragma unroll
            for (int dd = 1; dd < 16; dd <<= 1) mx = fmaxf(mx, __shfl_xor(mx, dd, 64));
            float sum = 0.f;
            #pragma unroll
            for (int st = 0; st < 16; ++st) {
                const float e = __expf(sc[st][r] - mx);
                sc[st][r] = e;
                sum += e;
            }
            #pragma unroll
            for (int dd = 1; dd < 16; dd <<= 1) sum += __shfl_xor(sum, dd, 64);
            const float inv = 1.f / sum;
            const int rl = l4 * 4 + r;
            #pragma unroll
            for (int st = 0; st < 16; ++st) {
                const int sg = st * 16 + l15;
                Pl[w][sg >> 3][rl][sg & 7] = f2bf(sc[st][r] * inv);
            }
        }
        f32x4 oacc[4];
        #pragma unroll
        for (int dt = 0; dt < 4; ++dt) oacc[dt] = (f32x4){0.f, 0.f, 0.f, 0.f};
        #pragma unroll
        for (int kt = 0; kt < 8; ++kt) {
            bf16x8 pa = *reinterpret_cast<const bf16x8*>(&Pl[w][kt * 4 + l4][l15][0]);
            #pragma unroll
            for (int dt = 0; dt < 4; ++dt) {
                bf16x8 vf = *reinterpret_cast<const bf16x8*>(&Vt[kt * 4 + l4][dt * 16 + l15][0]);
                oacc[dt] = __builtin_amdgcn_mfma_f32_16x16x32_bf16(pa, vf, oacc[dt], 0, 0, 0);
            }
        }
        #pragma unroll
        for (int dt = 0; dt < 4; ++dt)
            #pragma unroll
            for (int r = 0; r < 4; ++r)
                O[((size_t)(t0 + l4 * 4 + r) * 16 + n) * 1024 + hoff + dt * 16 + l15] = f2bf(oacc[dt][r]);
    }
}

// ---------------------------------------------------------------------------
// LayerNorm over D=1024, one wave per row (plain and fused-reduce variants)
// ---------------------------------------------------------------------------
__device__ __forceinline__ void ln_body(
    f32x4 (&v)[4], int row, int lane,
    const float* __restrict__ g, const float* __restrict__ b,
    float* __restrict__ xf, unsigned short* __restrict__ xb)
{
    float s = 0.f;
    #pragma unroll
    for (int i = 0; i < 4; ++i) s += v[i][0] + v[i][1] + v[i][2] + v[i][3];
    #pragma unroll
    for (int dd = 1; dd < 64; dd <<= 1) s += __shfl_xor(s, dd, 64);
    const float mu = s * (1.f / 1024.f);
    float q = 0.f;
    #pragma unroll
    for (int i = 0; i < 4; ++i)
        #pragma unroll
        for (int j = 0; j < 4; ++j) { const float d0 = v[i][j] - mu; q += d0 * d0; }
    #pragma unroll
    for (int dd = 1; dd < 64; dd <<= 1) q += __shfl_xor(q, dd, 64);
    const float rstd = rsqrtf(q * (1.f / 1024.f) + 1e-5f);
    #pragma unroll
    for (int i = 0; i < 4; ++i) {
        const int col = i * 256 + lane * 4;
        f32x4 gg = *reinterpret_cast<const f32x4*>(&g[col]);
        f32x4 bb = *reinterpret_cast<const f32x4*>(&b[col]);
        f32x4 y;
        #pragma unroll
        for (int j = 0; j < 4; ++j) y[j] = (v[i][j] - mu) * rstd * gg[j] + bb[j];
        if (xf) *reinterpret_cast<f32x4*>(&xf[(size_t)row * 1024 + col]) = y;
        if (xb) {
            u16x4 pk;
            #pragma unroll
            for (int j = 0; j < 4; ++j) pk[j] = f2bf(y[j]);
            *reinterpret_cast<u16x4*>(&xb[(size_t)row * 1024 + col]) = pk;
        }
    }
}

__global__ __launch_bounds__(256) void ln_kernel(
    const float* __restrict__ z, const float* __restrict__ g, const float* __restrict__ b,
    float* __restrict__ xf, unsigned short* __restrict__ xb)
{
    const int row  = blockIdx.x * 4 + (threadIdx.x >> 6);
    const int lane = threadIdx.x & 63;
    f32x4 v[4];
    #pragma unroll
    for (int i = 0; i < 4; ++i)
        v[i] = *reinterpret_cast<const f32x4*>(&z[(size_t)row * 1024 + i * 256 + lane * 4]);
    ln_body(v, row, lane, g, b, xf, xb);
}

__global__ __launch_bounds__(256) void ln_red2(
    const float* __restrict__ p0, const float* __restrict__ p1,
    const float* __restrict__ bias, const float* __restrict__ resid,
    const float* __restrict__ g, const float* __restrict__ b,
    float* __restrict__ xf, unsigned short* __restrict__ xb)
{
    const int row  = blockIdx.x * 4 + (threadIdx.x >> 6);
    const int lane = threadIdx.x & 63;
    f32x4 v[4];
    #pragma unroll
    for (int i = 0; i < 4; ++i) {
        const int col = i * 256 + lane * 4;
        const size_t o = (size_t)row * 1024 + col;
        f32x4 a0 = *reinterpret_cast<const f32x4*>(&p0[o]);
        f32x4 a1 = *reinterpret_cast<const f32x4*>(&p1[o]);
        f32x4 bs = *reinterpret_cast<const f32x4*>(&bias[col]);
        f32x4 rs = *reinterpret_cast<const f32x4*>(&resid[o]);
        v[i] = a0 + a1 + bs + rs;
    }
    ln_body(v, row, lane, g, b, xf, xb);
}

__global__ __launch_bounds__(256) void cvt_bf16(
    const float* __restrict__ in, unsigned short* __restrict__ out, int n)
{
    const int i = (blockIdx.x * 256 + threadIdx.x) * 4;
    if (i >= n) return;
    f32x4 v = *reinterpret_cast<const f32x4*>(&in[i]);
    u16x4 pk;
    #pragma unroll
    for (int j = 0; j < 4; ++j) pk[j] = f2bf(v[j]);
    *reinterpret_cast<u16x4*>(&out[i]) = pk;
}

// ---------------------------------------------------------------------------
// Per-layer weight pack (fp32->bf16, Q-scale folded):
//   [0,3DD) sa qkv  [3DD,6DD) ca qkv  [6DD,7DD) sa_wo  [7DD,8DD) ca_wo
//   [8DD,12DD) w1   [12DD,16DD) w2
// ---------------------------------------------------------------------------
__global__ __launch_bounds__(256) void pack_layer_w(
    const float* __restrict__ sa_wq, const float* __restrict__ sa_wk, const float* __restrict__ sa_wv,
    const float* __restrict__ ca_wq, const float* __restrict__ ca_wk, const float* __restrict__ ca_wv,
    const float* __restrict__ sa_wo, const float* __restrict__ ca_wo,
    const float* __restrict__ w1,   const float* __restrict__ w2,
    unsigned short* __restrict__ dst, int layer)
{
    const size_t DD = 1024u * 1024u;
    const size_t e  = ((size_t)blockIdx.x * 256 + threadIdx.x) * 4;
    const float* src;
    float scale = 1.f;
    if (e < 3 * DD) {
        const int part = (int)(e / DD);
        src = (part == 0 ? sa_wq : part == 1 ? sa_wk : sa_wv) + layer * DD + (e % DD);
        if (part == 0) scale = 0.125f;
    } else if (e < 6 * DD) {
        const size_t r = e - 3 * DD;
        const int part = (int)(r / DD);
        src = (part == 0 ? ca_wq : part == 1 ? ca_wk : ca_wv) + layer * DD + (r % DD);
        if (part == 0) scale = 0.125f;
    } else if (e < 7 * DD)  { src = sa_wo + layer * DD + (e - 6 * DD); }
    else if (e < 8 * DD)    { src = ca_wo + layer * DD + (e - 7 * DD); }
    else if (e < 12 * DD)   { src = w1 + (size_t)layer * 4 * DD + (e - 8 * DD); }
    else                    { src = w2 + (size_t)layer * 4 * DD + (e - 12 * DD); }
    f32x4 v = *reinterpret_cast<const f32x4*>(src);
    u16x4 pk;
    #pragma unroll
    for (int j = 0; j < 4; ++j) pk[j] = f2bf(v[j] * scale);
    *reinterpret_cast<u16x4*>(&dst[e]) = pk;
}

__global__ __launch_bounds__(256) void pack_bias(
    const float* __restrict__ sa_bq, const float* __restrict__ sa_bk, const float* __restrict__ sa_bv,
    const float* __restrict__ ca_bq, const float* __restrict__ ca_bk, const float* __restrict__ ca_bv,
    float* __restrict__ sab, float* __restrict__ cab)
{
    const int idx = blockIdx.x * 256 + threadIdx.x;
    const int half = idx / 12288;
    const int r    = idx % 12288;
    const int l    = r / 3072;
    const int pc   = r % 3072;
    const int part = pc >> 10;
    const int c    = pc & 1023;
    const float* src = half == 0 ? (part == 0 ? sa_bq : part == 1 ? sa_bk : sa_bv)
                                 : (part == 0 ? ca_bq : part == 1 ? ca_bk : ca_bv);
    const float v = src[l * 1024 + c] * (part == 0 ? 0.125f : 1.f);
    (half ? cab : sab)[l * 3072 + pc] = v;
}

// ---------------------------------------------------------------------------
extern "C" void kernel_launch(void* const* d_in, const int* in_sizes, int n_in,
                              void* d_out, int out_size, void* d_ws, size_t ws_size,
                              hipStream_t stream)
{
    (void)in_sizes; (void)n_in; (void)out_size; (void)ws_size;
    const int M  = 4096;
    const int Dm = 1024;
    const size_t DD = (size_t)Dm * Dm;

    const float* tgt   = (const float*)d_in[0];
    const float* mem   = (const float*)d_in[1];
    const float* sa_wq = (const float*)d_in[2];
    const float* sa_wk = (const float*)d_in[3];
    const float* sa_wv = (const float*)d_in[4];
    const float* sa_wo = (const float*)d_in[5];
    const float* sa_bq = (const float*)d_in[6];
    const float* sa_bk = (const float*)d_in[7];
    const float* sa_bv = (const float*)d_in[8];
    const float* sa_bo = (const float*)d_in[9];
    const float* ca_wq = (const float*)d_in[10];
    const float* ca_wk = (const float*)d_in[11];
    const float* ca_wv = (const float*)d_in[12];
    const float* ca_wo = (const float*)d_in[13];
    const float* ca_bq = (const float*)d_in[14];
    const float* ca_bk = (const float*)d_in[15];
    const float* ca_bv = (const float*)d_in[16];
    const float* ca_bo = (const float*)d_in[17];
    const float* w1    = (const float*)d_in[18];
    const float* b1    = (const float*)d_in[19];
    const float* w2    = (const float*)d_in[20];
    const float* b2    = (const float*)d_in[21];
    const float* ln1g  = (const float*)d_in[22];
    const float* ln1b  = (const float*)d_in[23];
    const float* ln2g  = (const float*)d_in[24];
    const float* ln2b  = (const float*)d_in[25];
    const float* ln3g  = (const float*)d_in[26];
    const float* ln3b  = (const float*)d_in[27];
    const float* lnfg  = (const float*)d_in[28];
    const float* lnfb  = (const float*)d_in[29];

    char* p = (char*)d_ws;
    float*          x_f    = (float*)p;          p += (size_t)M * Dm * 4;
    unsigned short* x_b    = (unsigned short*)p; p += (size_t)M * Dm * 2;
    unsigned short* mem_b  = (unsigned short*)p; p += (size_t)M * Dm * 2;
    unsigned short* qkv_b  = (unsigned short*)p; p += (size_t)M * 3072 * 2;
    unsigned short* cakv_b = (unsigned short*)p; p += (size_t)M * 2048 * 2;
    unsigned short* caq_b  = (unsigned short*)p; p += (size_t)M * Dm * 2;
    unsigned short* ao_b   = (unsigned short*)p; p += (size_t)M * Dm * 2;
    unsigned short* wpack  = (unsigned short*)p; p += 16 * DD * 2;
    float*          sab    = (float*)p;          p += 4 * 3072 * 4;
    float*          cab    = (float*)p;          p += 4 * 3072 * 4;
    unsigned short* h_b    = qkv_b;                                          // [4096][4096] bf16
    float*          par0   = (float*)((char*)qkv_b + (size_t)M * 4096 * 2);  // dead cakv tail+caq+ao
    float*          par1   = (float*)wpack;                                  // dead packed weights
    float*          z_f    = (float*)d_out;

    dim3 blk(256), blk5(512);
    auto gemm64 = [&](const unsigned short* A, const unsigned short* Bw, const float* bias,
                      const float* resid, unsigned short* ob, float* of, int N, int K, int mode) {
        dim3 grid(N / 128, M / 64);
        gemm_bt64<<<grid, blk, 0, stream>>>(A, Bw, bias, resid, ob, of, M, N, K, mode);
    };

    cvt_bf16<<<4096, blk, 0, stream>>>(tgt, x_b, M * Dm);
    cvt_bf16<<<4096, blk, 0, stream>>>(mem, mem_b, M * Dm);
    pack_bias<<<96, blk, 0, stream>>>(sa_bq, sa_bk, sa_bv, ca_bq, ca_bk, ca_bv, sab, cab);

    const float* res = tgt;
    for (int i = 0; i < 4; ++i) {
        pack_layer_w<<<16384, blk, 0, stream>>>(sa_wq, sa_wk, sa_wv, ca_wq, ca_wk, ca_wv,
                                                sa_wo, ca_wo, w1, w2, wpack, i);
        // --- self-attention (fused QKV, N=3072) ---
        gemm256<<<dim3(12, 16, 1), blk5, 0, stream>>>(x_b, wpack, sab + i * 3072,
            qkv_b, nullptr, nullptr, 3072, 1024, 1024, 0);
        attn_fused<<<256, blk, 0, stream>>>(qkv_b, 3072, qkv_b + 1024, 3072, qkv_b + 2048, 3072, ao_b, 1);
        gemm64(ao_b, wpack + 6 * DD, sa_bo + i * Dm, res, nullptr, z_f, 1024, 1024, 2);
        ln_kernel<<<1024, blk, 0, stream>>>(z_f, ln1g + i * Dm, ln1b + i * Dm, x_f, x_b);
        res = x_f;
        // --- cross-attention (Q from x; fused KV from memory, N=2048) ---
        gemm64(x_b, wpack + 3 * DD, cab + i * 3072, nullptr, caq_b, nullptr, 1024, 1024, 0);
        gemm256<<<dim3(8, 16, 1), blk5, 0, stream>>>(mem_b, wpack + 4 * DD, cab + i * 3072 + 1024,
            cakv_b, nullptr, nullptr, 2048, 1024, 1024, 0);
        attn_fused<<<256, blk, 0, stream>>>(caq_b, 1024, cakv_b, 2048, cakv_b + 1024, 2048, ao_b, 0);
        gemm64(ao_b, wpack + 7 * DD, ca_bo + i * Dm, x_f, nullptr, z_f, 1024, 1024, 2);
        ln_kernel<<<1024, blk, 0, stream>>>(z_f, ln2g + i * Dm, ln2b + i * Dm, x_f, x_b);
        // --- FFN ---
        gemm256<<<dim3(16, 16, 1), blk5, 0, stream>>>(x_b, wpack + 8 * DD, b1 + i * 4096,
            h_b, nullptr, nullptr, 4096, 1024, 1024, 1);
        gemm256<<<dim3(4, 16, 2), blk5, 0, stream>>>(h_b, wpack + 12 * DD, nullptr,
            nullptr, par0, par1, 1024, 4096, 2048, 3);
        ln_red2<<<1024, blk, 0, stream>>>(par0, par1, b2 + i * Dm, x_f,
            ln3g + i * Dm, ln3b + i * Dm, x_f, x_b);
    }
    ln_kernel<<<1024, blk, 0, stream>>>(x_f, lnfg, lnfb, (float*)d_out, nullptr);
}